// Round 1
// baseline (7562.630 us; speedup 1.0000x reference)
//
#include <hip/hip_runtime.h>
#include <math.h>

#define BB 16
#define TT 512
#define CC 1024
#define HH 16
#define HD 64
#define NT (BB*TT)   // 8192 rows

// ---------------- LayerNorm: one block (256 thr) per row of 1024 ----------------
__global__ __launch_bounds__(256) void ln_kernel(const float* __restrict__ x,
                                                 const float* __restrict__ g,
                                                 const float* __restrict__ b,
                                                 float* __restrict__ out) {
    int row = blockIdx.x;
    const float* xr = x + (size_t)row * CC;
    float* orow = out + (size_t)row * CC;
    int tid = threadIdx.x;
    float v[4];
    float lsum = 0.f, lsq = 0.f;
#pragma unroll
    for (int i = 0; i < 4; i++) {
        v[i] = xr[tid + 256 * i];
        lsum += v[i];
        lsq  += v[i] * v[i];
    }
    __shared__ float ssum[4], ssq[4];
#pragma unroll
    for (int o = 32; o > 0; o >>= 1) {
        lsum += __shfl_down(lsum, o);
        lsq  += __shfl_down(lsq, o);
    }
    int wid = tid >> 6, lane = tid & 63;
    if (lane == 0) { ssum[wid] = lsum; ssq[wid] = lsq; }
    __syncthreads();
    if (tid == 0) {
        float s = 0.f, q = 0.f;
#pragma unroll
        for (int i = 0; i < 4; i++) { s += ssum[i]; q += ssq[i]; }
        float mu = s / CC;
        float var = q / CC - mu * mu;
        ssum[0] = mu;
        ssq[0] = rsqrtf(var + 1e-5f);
    }
    __syncthreads();
    float mu = ssum[0], rstd = ssq[0];
#pragma unroll
    for (int i = 0; i < 4; i++) {
        int c = tid + 256 * i;
        orow[c] = (v[i] - mu) * rstd * g[c] + b[c];
    }
}

// ---------------- Generic tiled fp32 GEMM: C[M,N] = A[M,K] @ W[K,N] + epilogue --------
// 64x64 tile, BK=16, 256 threads, 4x4 per-thread microtile.
enum { EPI_BIAS = 0, EPI_BIAS_RES = 1, EPI_BIAS_GELU = 2 };

template <int EPI>
__global__ __launch_bounds__(256) void gemm_kernel(const float* __restrict__ A,
                                                   const float* __restrict__ W,
                                                   const float* __restrict__ bias,
                                                   const float* __restrict__ R,
                                                   float* __restrict__ C,
                                                   int M, int N, int K) {
    const int BM = 64, BN = 64, BK = 16;
    __shared__ float As[BK][BM];
    __shared__ float Ws[BK][BN];
    int tid = threadIdx.x;
    int tx = tid & 15, ty = tid >> 4;
    int bm = blockIdx.y * BM, bn = blockIdx.x * BN;
    float acc[4][4] = {};

    for (int k0 = 0; k0 < K; k0 += BK) {
        // A tile: As[kk][m] <- A[(bm+m)*K + k0+kk]   (16 consecutive k per 16 lanes)
#pragma unroll
        for (int i = 0; i < 4; i++) {
            int t = tid + i * 256;
            int m = t >> 4;
            int kk = t & 15;
            As[kk][m] = A[(size_t)(bm + m) * K + (k0 + kk)];
        }
        // W tile: Ws[kk][n] <- W[(k0+kk)*N + bn+n]   (fully coalesced rows)
#pragma unroll
        for (int i = 0; i < 4; i++) {
            int t = tid + i * 256;
            int kk = t >> 6;
            int n = t & 63;
            Ws[kk][n] = W[(size_t)(k0 + kk) * N + (bn + n)];
        }
        __syncthreads();
#pragma unroll
        for (int kk = 0; kk < BK; kk++) {
            float a[4], w[4];
#pragma unroll
            for (int i = 0; i < 4; i++) a[i] = As[kk][ty * 4 + i];
#pragma unroll
            for (int j = 0; j < 4; j++) w[j] = Ws[kk][tx * 4 + j];
#pragma unroll
            for (int i = 0; i < 4; i++)
#pragma unroll
                for (int j = 0; j < 4; j++)
                    acc[i][j] += a[i] * w[j];
        }
        __syncthreads();
    }

#pragma unroll
    for (int i = 0; i < 4; i++) {
        int row = bm + ty * 4 + i;
#pragma unroll
        for (int j = 0; j < 4; j++) {
            int col = bn + tx * 4 + j;
            float v = acc[i][j] + bias[col];
            if (EPI == EPI_BIAS_GELU) {
                float u = 0.7978845608028654f * (v + 0.044715f * v * v * v);
                v = 0.5f * v * (1.0f + tanhf(u));
            } else if (EPI == EPI_BIAS_RES) {
                v += R[(size_t)row * N + col];
            }
            C[(size_t)row * N + col] = v;
        }
    }
}

// ---------------- Attention: one wave per (b,h,q); lane = head dim ----------------
// qkv layout: [B*T, 3*C]; q at col h*64+d, k at C + h*64+d, v at 2C + h*64+d
__global__ __launch_bounds__(64) void attn_kernel(const float* __restrict__ qkv,
                                                  const int* __restrict__ mask,
                                                  float* __restrict__ y) {
    int q = blockIdx.x;   // T
    int h = blockIdx.y;   // H
    int b = blockIdx.z;   // B
    int d = threadIdx.x;  // 64 lanes = head dim
    const size_t row3 = 3 * CC;
    const float* qp = qkv + (size_t)(b * TT + q) * row3 + h * HD;
    float qv = qp[d] * 0.125f;  // 1/sqrt(64) folded into q
    const float* kbase = qkv + (size_t)b * TT * row3 + CC + h * HD;
    const float* vbase = kbase + CC;
    const int* mrow = mask + b * TT;

    float m = -INFINITY, l = 0.f, acc = 0.f;
    for (int k = 0; k < TT; k++) {
        float kd = kbase[(size_t)k * row3 + d];
        float prod = qv * kd;
#pragma unroll
        for (int o = 32; o > 0; o >>= 1) prod += __shfl_xor(prod, o);
        float s = prod;
        if (mrow[k] == 0) s = -INFINITY;
        float mn = fmaxf(m, s);
        float scale = (mn == -INFINITY) ? 1.f : expf(m - mn);
        float p = (s == -INFINITY) ? 0.f : ((mn == -INFINITY) ? 0.f : expf(s - mn));
        float vd = vbase[(size_t)k * row3 + d];
        acc = acc * scale + p * vd;
        l = l * scale + p;
        m = mn;
    }
    y[(size_t)(b * TT + q) * CC + h * HD + d] = acc / l;
}

extern "C" void kernel_launch(void* const* d_in, const int* in_sizes, int n_in,
                              void* d_out, int out_size, void* d_ws, size_t ws_size,
                              hipStream_t stream) {
    const float* x      = (const float*)d_in[0];
    const int*   mask   = (const int*)d_in[1];
    const float* ln1_g  = (const float*)d_in[2];
    const float* ln1_b  = (const float*)d_in[3];
    const float* w_attn = (const float*)d_in[4];
    const float* b_attn = (const float*)d_in[5];
    const float* w_o    = (const float*)d_in[6];
    const float* b_o    = (const float*)d_in[7];
    const float* ln2_g  = (const float*)d_in[8];
    const float* ln2_b  = (const float*)d_in[9];
    const float* w_fc   = (const float*)d_in[10];
    const float* b_fc   = (const float*)d_in[11];
    const float* w_fc2  = (const float*)d_in[12];
    const float* b_fc2  = (const float*)d_in[13];
    float* out = (float*)d_out;

    // Workspace regions (reused along the dependency chain):
    //   A (32MB):  h -> y -> h2
    //   Bm (128MB): qkv -> act
    //   Cm (32MB): x1
    char* ws = (char*)d_ws;
    float* regA = (float*)ws;                                   // NT*CC
    float* regB = (float*)(ws + (size_t)NT * CC * 4);           // NT*4*CC
    float* regC = (float*)(ws + (size_t)NT * CC * 4 * 5);       // NT*CC
    float* h   = regA;
    float* qkv = regB;
    float* y   = regA;
    float* x1  = regC;
    float* h2  = regA;
    float* act = regB;

    // 1. LN1
    ln_kernel<<<NT, 256, 0, stream>>>(x, ln1_g, ln1_b, h);
    // 2. qkv = h @ w_attn + b_attn     [8192,1024]x[1024,3072]
    gemm_kernel<EPI_BIAS><<<dim3(3 * CC / 64, NT / 64), 256, 0, stream>>>(
        h, w_attn, b_attn, nullptr, qkv, NT, 3 * CC, CC);
    // 3. attention -> y [B*T, C]
    attn_kernel<<<dim3(TT, HH, BB), 64, 0, stream>>>(qkv, mask, y);
    // 4. x1 = y @ w_o + b_o + x
    gemm_kernel<EPI_BIAS_RES><<<dim3(CC / 64, NT / 64), 256, 0, stream>>>(
        y, w_o, b_o, x, x1, NT, CC, CC);
    // 5. LN2
    ln_kernel<<<NT, 256, 0, stream>>>(x1, ln2_g, ln2_b, h2);
    // 6. act = gelu(h2 @ w_fc + b_fc)  [8192,1024]x[1024,4096]
    gemm_kernel<EPI_BIAS_GELU><<<dim3(4 * CC / 64, NT / 64), 256, 0, stream>>>(
        h2, w_fc, b_fc, nullptr, act, NT, 4 * CC, CC);
    // 7. out = act @ w_fc2 + b_fc2 + x1
    gemm_kernel<EPI_BIAS_RES><<<dim3(CC / 64, NT / 64), 256, 0, stream>>>(
        act, w_fc2, b_fc2, x1, out, NT, CC, 4 * CC);
}

// Round 2
// 784.728 us; speedup vs baseline: 9.6373x; 9.6373x over previous
//
#include <hip/hip_runtime.h>
#include <math.h>
#include <stdint.h>

#define BB 16
#define TT 512
#define CC 1024
#define HH 16
#define HD 64
#define NT (BB*TT)   // 8192 rows

typedef __bf16 bf16x8 __attribute__((ext_vector_type(8)));
typedef float f32x4 __attribute__((ext_vector_type(4)));

__device__ __forceinline__ unsigned short f2bf(float x) {
    union { float f; unsigned u; } v; v.f = x;
    unsigned r = v.u + 0x7fffu + ((v.u >> 16) & 1u);
    return (unsigned short)(r >> 16);
}

__device__ __forceinline__ void gload_lds16(const void* g, void* l) {
    __builtin_amdgcn_global_load_lds((const __attribute__((address_space(1))) uint32_t*)g,
                                     (__attribute__((address_space(3))) uint32_t*)l, 16, 0, 0);
}

// ---------------- weight transpose+convert: in[K,N] fp32 -> out[N,K] bf16 ----------------
__global__ __launch_bounds__(256) void tcvt_kernel(const float* __restrict__ in,
                                                   unsigned short* __restrict__ out,
                                                   int K, int N) {
    __shared__ float Tt[32][33];
    int n0 = blockIdx.x * 32, k0 = blockIdx.y * 32;
    int t = threadIdx.x;
#pragma unroll
    for (int i = 0; i < 4; i++) {
        int idx = i * 256 + t; int r = idx >> 5, c = idx & 31;
        Tt[r][c] = in[(size_t)(k0 + r) * N + n0 + c];
    }
    __syncthreads();
#pragma unroll
    for (int i = 0; i < 4; i++) {
        int idx = i * 256 + t; int r = idx >> 5, c = idx & 31; // r=n-local, c=k-local
        out[(size_t)(n0 + r) * K + k0 + c] = f2bf(Tt[c][r]);
    }
}

// ---------------- LayerNorm -> bf16 out ----------------
__global__ __launch_bounds__(256) void ln_kernel(const float* __restrict__ x,
                                                 const float* __restrict__ g,
                                                 const float* __restrict__ b,
                                                 unsigned short* __restrict__ out) {
    int row = blockIdx.x;
    const float* xr = x + (size_t)row * CC;
    unsigned short* orow = out + (size_t)row * CC;
    int tid = threadIdx.x;
    float v[4];
    float lsum = 0.f, lsq = 0.f;
#pragma unroll
    for (int i = 0; i < 4; i++) {
        v[i] = xr[tid + 256 * i];
        lsum += v[i];
        lsq  += v[i] * v[i];
    }
    __shared__ float ssum[4], ssq[4];
#pragma unroll
    for (int o = 32; o > 0; o >>= 1) {
        lsum += __shfl_down(lsum, o);
        lsq  += __shfl_down(lsq, o);
    }
    int wid = tid >> 6, lane = tid & 63;
    if (lane == 0) { ssum[wid] = lsum; ssq[wid] = lsq; }
    __syncthreads();
    if (tid == 0) {
        float s = 0.f, q = 0.f;
#pragma unroll
        for (int i = 0; i < 4; i++) { s += ssum[i]; q += ssq[i]; }
        float mu = s / CC;
        float var = q / CC - mu * mu;
        ssum[0] = mu;
        ssq[0] = rsqrtf(var + 1e-5f);
    }
    __syncthreads();
    float mu = ssum[0], rstd = ssq[0];
#pragma unroll
    for (int i = 0; i < 4; i++) {
        int c = tid + 256 * i;
        orow[c] = f2bf((v[i] - mu) * rstd * g[c] + b[c]);
    }
}

// ---------------- bf16 MFMA GEMM: C[M,N] = A[M,K](bf16) @ Bt[N,K](bf16)^T + epilogue ------
// 128x128 tile, BK=32, 256 thr = 4 waves (2x2 of 64x64), 4x4 MFMA 16x16x32 tiles per wave.
enum { EPI_BIAS_F32 = 0, EPI_BIAS_RES_F32 = 1, EPI_BIAS_GELU_BF16 = 2 };

template <int EPI>
__global__ __launch_bounds__(256) void mgemm(const unsigned short* __restrict__ A,
                                             const unsigned short* __restrict__ Bt,
                                             const float* __restrict__ bias,
                                             const float* __restrict__ R,
                                             float* __restrict__ Cf,
                                             unsigned short* __restrict__ Cb,
                                             int M, int N, int K) {
    __shared__ __align__(16) unsigned short As[128 * 32];
    __shared__ __align__(16) unsigned short Bs[128 * 32];
    int tid = threadIdx.x;
    int w = tid >> 6, lane = tid & 63;
    int bm = blockIdx.y * 128, bn = blockIdx.x * 128;
    int wr = (w >> 1) * 64, wc = (w & 1) * 64;

    // staging: thread covers 16B slots {tid, tid+256}; slot s -> row s>>2, k-part s&3.
    const unsigned short* gA0 = A + (size_t)(bm + (tid >> 2)) * K + (tid & 3) * 8;
    const unsigned short* gA1 = A + (size_t)(bm + 64 + (tid >> 2)) * K + (tid & 3) * 8;
    const unsigned short* gB0 = Bt + (size_t)(bn + (tid >> 2)) * K + (tid & 3) * 8;
    const unsigned short* gB1 = Bt + (size_t)(bn + 64 + (tid >> 2)) * K + (tid & 3) * 8;
    char* lA0 = (char*)As + w * 1024;
    char* lA1 = (char*)As + 4096 + w * 1024;
    char* lB0 = (char*)Bs + w * 1024;
    char* lB1 = (char*)Bs + 4096 + w * 1024;

    int ml = lane & 15, quad = lane >> 4;
    const bf16x8* As8 = (const bf16x8*)As;
    const bf16x8* Bs8 = (const bf16x8*)Bs;
    const bf16x8* pa = As8 + (wr + ml) * 4 + quad;
    const bf16x8* pb = Bs8 + (wc + ml) * 4 + quad;

    f32x4 acc[4][4] = {};

    for (int k0 = 0; k0 < K; k0 += 32) {
        gload_lds16(gA0 + k0, lA0);
        gload_lds16(gA1 + k0, lA1);
        gload_lds16(gB0 + k0, lB0);
        gload_lds16(gB1 + k0, lB1);
        __syncthreads();
        bf16x8 a[4], bb[4];
#pragma unroll
        for (int ti = 0; ti < 4; ti++) a[ti] = pa[ti * 64];
#pragma unroll
        for (int tj = 0; tj < 4; tj++) bb[tj] = pb[tj * 64];
#pragma unroll
        for (int ti = 0; ti < 4; ti++)
#pragma unroll
            for (int tj = 0; tj < 4; tj++)
                acc[ti][tj] = __builtin_amdgcn_mfma_f32_16x16x32_bf16(a[ti], bb[tj], acc[ti][tj], 0, 0, 0);
        __syncthreads();
    }

    // epilogue: D[m][n]: n = lane&15 (col), m = quad*4 + reg
#pragma unroll
    for (int ti = 0; ti < 4; ti++) {
#pragma unroll
        for (int tj = 0; tj < 4; tj++) {
            int n = bn + wc + tj * 16 + ml;
            int mbase = bm + wr + ti * 16 + quad * 4;
            float bv = bias[n];
#pragma unroll
            for (int reg = 0; reg < 4; reg++) {
                int m = mbase + reg;
                float v = acc[ti][tj][reg] + bv;
                if (EPI == EPI_BIAS_GELU_BF16) {
                    float u = 0.7978845608028654f * (v + 0.044715f * v * v * v);
                    v = 0.5f * v * (1.0f + tanhf(u));
                    Cb[(size_t)m * N + n] = f2bf(v);
                } else if (EPI == EPI_BIAS_RES_F32) {
                    v += R[(size_t)m * N + n];
                    Cf[(size_t)m * N + n] = v;
                } else {
                    Cf[(size_t)m * N + n] = v;
                }
            }
        }
    }
}

// ---------------- Flash attention (fp32): block = (b,h,64-query tile) ----------------
// qkv [B*T, 3C] fp32; out y bf16 [B*T, C]
__global__ __launch_bounds__(256) void attn_kernel(const float* __restrict__ qkv,
                                                   const int* __restrict__ mask,
                                                   unsigned short* __restrict__ yb) {
    __shared__ __align__(16) float Qs[64][68];
    __shared__ __align__(16) float Ks[64][68];   // reused as Pt[k][row]
    __shared__ __align__(16) float Vs[64][68];
    __shared__ int ms[64];
    int qt = blockIdx.x, h = blockIdx.y, b = blockIdx.z;
    int tid = threadIdx.x;
    int tx = tid & 15, ty = tid >> 4;
    const size_t row3 = 3 * CC;
    const float* qbase = qkv + (size_t)(b * TT + qt * 64) * row3 + h * HD;
    const float* kbase = qkv + (size_t)(b * TT) * row3 + CC + h * HD;
    const float* vbase = kbase + CC;

    // load Q tile (scaled by 1/sqrt(64))
#pragma unroll
    for (int i = 0; i < 4; i++) {
        int idx = i * 256 + tid; int r = idx >> 4, c4 = idx & 15;
        float4 v = *(const float4*)(qbase + (size_t)r * row3 + c4 * 4);
        v.x *= 0.125f; v.y *= 0.125f; v.z *= 0.125f; v.w *= 0.125f;
        *(float4*)&Qs[r][c4 * 4] = v;
    }

    float m_i[4], l_i[4];
    float o0[4], o1[4], o2[4], o3[4];  // o{ii}[jj]: row ty*4+ii, col tx*4+jj
#pragma unroll
    for (int ii = 0; ii < 4; ii++) {
        m_i[ii] = -1e30f; l_i[ii] = 0.f;
        o0[ii] = 0.f; o1[ii] = 0.f; o2[ii] = 0.f; o3[ii] = 0.f;
    }

    for (int k0 = 0; k0 < TT; k0 += 64) {
#pragma unroll
        for (int i = 0; i < 4; i++) {
            int idx = i * 256 + tid; int r = idx >> 4, c4 = idx & 15;
            *(float4*)&Ks[r][c4 * 4] = *(const float4*)(kbase + (size_t)(k0 + r) * row3 + c4 * 4);
            *(float4*)&Vs[r][c4 * 4] = *(const float4*)(vbase + (size_t)(k0 + r) * row3 + c4 * 4);
        }
        if (tid < 64) ms[tid] = mask[b * TT + k0 + tid];
        __syncthreads();

        // S = Q K^T, cols strided: col(jj) = tx + jj*16
        float s[4][4] = {};
#pragma unroll 8
        for (int d0 = 0; d0 < 64; d0 += 4) {
            float4 a[4], bv[4];
#pragma unroll
            for (int ii = 0; ii < 4; ii++) a[ii] = *(const float4*)&Qs[ty * 4 + ii][d0];
#pragma unroll
            for (int jj = 0; jj < 4; jj++) bv[jj] = *(const float4*)&Ks[tx + jj * 16][d0];
#pragma unroll
            for (int ii = 0; ii < 4; ii++)
#pragma unroll
                for (int jj = 0; jj < 4; jj++)
                    s[ii][jj] += a[ii].x * bv[jj].x + a[ii].y * bv[jj].y
                               + a[ii].z * bv[jj].z + a[ii].w * bv[jj].w;
        }
#pragma unroll
        for (int jj = 0; jj < 4; jj++) {
            if (ms[tx + jj * 16] == 0) {
#pragma unroll
                for (int ii = 0; ii < 4; ii++) s[ii][jj] = -1e30f;
            }
        }
        // online softmax
        float mt[4], alpha[4], ssum[4];
#pragma unroll
        for (int ii = 0; ii < 4; ii++) {
            mt[ii] = fmaxf(fmaxf(s[ii][0], s[ii][1]), fmaxf(s[ii][2], s[ii][3]));
        }
#pragma unroll
        for (int off = 1; off < 16; off <<= 1)
#pragma unroll
            for (int ii = 0; ii < 4; ii++) mt[ii] = fmaxf(mt[ii], __shfl_xor(mt[ii], off));
#pragma unroll
        for (int ii = 0; ii < 4; ii++) {
            float mn = fmaxf(m_i[ii], mt[ii]);
            alpha[ii] = __expf(m_i[ii] - mn);
            m_i[ii] = mn;
            ssum[ii] = 0.f;
#pragma unroll
            for (int jj = 0; jj < 4; jj++) {
                s[ii][jj] = __expf(s[ii][jj] - mn);
                ssum[ii] += s[ii][jj];
            }
        }
#pragma unroll
        for (int off = 1; off < 16; off <<= 1)
#pragma unroll
            for (int ii = 0; ii < 4; ii++) ssum[ii] += __shfl_xor(ssum[ii], off);
#pragma unroll
        for (int ii = 0; ii < 4; ii++) {
            l_i[ii] = l_i[ii] * alpha[ii] + ssum[ii];
            o0[ii] *= alpha[ii]; o1[ii] *= alpha[ii]; o2[ii] *= alpha[ii]; o3[ii] *= alpha[ii];
        }
        __syncthreads();  // everyone done reading Ks
        // store P transposed into Ks buffer: Pt[k][row]
#pragma unroll
        for (int ii = 0; ii < 4; ii++)
#pragma unroll
            for (int jj = 0; jj < 4; jj++)
                Ks[tx + jj * 16][ty * 4 + ii] = s[ii][jj];
        __syncthreads();
        // O += P V : o{ii}[jj], col jj = tx*4+jj (contiguous)
        for (int k = 0; k < 64; k++) {
            float4 pr = *(const float4*)&Ks[k][ty * 4];
            float4 vv = *(const float4*)&Vs[k][tx * 4];
            o0[0] += pr.x * vv.x; o0[1] += pr.x * vv.y; o0[2] += pr.x * vv.z; o0[3] += pr.x * vv.w;
            o1[0] += pr.y * vv.x; o1[1] += pr.y * vv.y; o1[2] += pr.y * vv.z; o1[3] += pr.y * vv.w;
            o2[0] += pr.z * vv.x; o2[1] += pr.z * vv.y; o2[2] += pr.z * vv.z; o2[3] += pr.z * vv.w;
            o3[0] += pr.w * vv.x; o3[1] += pr.w * vv.y; o3[2] += pr.w * vv.z; o3[3] += pr.w * vv.w;
        }
        __syncthreads();  // before next tile overwrites Ks/Vs
    }

    // epilogue
#pragma unroll
    for (int ii = 0; ii < 4; ii++) {
        float inv = 1.f / l_i[ii];
        int q = qt * 64 + ty * 4 + ii;
        unsigned short* yr = yb + (size_t)(b * TT + q) * CC + h * HD + tx * 4;
        float* op = (ii == 0) ? o0 : (ii == 1) ? o1 : (ii == 2) ? o2 : o3;
        yr[0] = f2bf(op[0] * inv);
        yr[1] = f2bf(op[1] * inv);
        yr[2] = f2bf(op[2] * inv);
        yr[3] = f2bf(op[3] * inv);
    }
}

extern "C" void kernel_launch(void* const* d_in, const int* in_sizes, int n_in,
                              void* d_out, int out_size, void* d_ws, size_t ws_size,
                              hipStream_t stream) {
    const float* x      = (const float*)d_in[0];
    const int*   mask   = (const int*)d_in[1];
    const float* ln1_g  = (const float*)d_in[2];
    const float* ln1_b  = (const float*)d_in[3];
    const float* w_attn = (const float*)d_in[4];
    const float* b_attn = (const float*)d_in[5];
    const float* w_o    = (const float*)d_in[6];
    const float* b_o    = (const float*)d_in[7];
    const float* ln2_g  = (const float*)d_in[8];
    const float* ln2_b  = (const float*)d_in[9];
    const float* w_fc   = (const float*)d_in[10];
    const float* b_fc   = (const float*)d_in[11];
    const float* w_fc2  = (const float*)d_in[12];
    const float* b_fc2  = (const float*)d_in[13];
    float* out = (float*)d_out;

    char* ws = (char*)d_ws;
    size_t off = 0;
    unsigned short* wt_attn = (unsigned short*)(ws + off); off += (size_t)3 * CC * CC * 2;  // 6MB
    unsigned short* wt_o    = (unsigned short*)(ws + off); off += (size_t)CC * CC * 2;      // 2MB
    unsigned short* wt_fc   = (unsigned short*)(ws + off); off += (size_t)4 * CC * CC * 2;  // 8MB
    unsigned short* wt_fc2  = (unsigned short*)(ws + off); off += (size_t)4 * CC * CC * 2;  // 8MB
    float* qkv              = (float*)(ws + off);                                            // 96MB (reused for act)
    unsigned short* act     = (unsigned short*)(ws + off); off += (size_t)NT * 3 * CC * 4;
    unsigned short* hb      = (unsigned short*)(ws + off);                                   // 16MB (reused for y)
    unsigned short* yb      = (unsigned short*)(ws + off); off += (size_t)NT * CC * 2;
    float* x1               = (float*)(ws + off); off += (size_t)NT * CC * 4;                // 32MB
    unsigned short* h2b     = (unsigned short*)(ws + off); off += (size_t)NT * CC * 2;       // 16MB

    // weight transpose+convert: W[K,N] f32 -> Wt[N,K] bf16
    tcvt_kernel<<<dim3(3 * CC / 32, CC / 32), 256, 0, stream>>>(w_attn, wt_attn, CC, 3 * CC);
    tcvt_kernel<<<dim3(CC / 32, CC / 32), 256, 0, stream>>>(w_o, wt_o, CC, CC);
    tcvt_kernel<<<dim3(4 * CC / 32, CC / 32), 256, 0, stream>>>(w_fc, wt_fc, CC, 4 * CC);
    tcvt_kernel<<<dim3(CC / 32, 4 * CC / 32), 256, 0, stream>>>(w_fc2, wt_fc2, 4 * CC, CC);

    // 1. LN1 -> bf16
    ln_kernel<<<NT, 256, 0, stream>>>(x, ln1_g, ln1_b, hb);
    // 2. qkv = h @ w_attn + b_attn (f32 out)
    mgemm<EPI_BIAS_F32><<<dim3(3 * CC / 128, NT / 128), 256, 0, stream>>>(
        hb, wt_attn, b_attn, nullptr, qkv, nullptr, NT, 3 * CC, CC);
    // 3. attention -> y bf16
    attn_kernel<<<dim3(TT / 64, HH, BB), 256, 0, stream>>>(qkv, mask, yb);
    // 4. x1 = y @ w_o + b_o + x
    mgemm<EPI_BIAS_RES_F32><<<dim3(CC / 128, NT / 128), 256, 0, stream>>>(
        yb, wt_o, b_o, x, x1, nullptr, NT, CC, CC);
    // 5. LN2 -> bf16
    ln_kernel<<<NT, 256, 0, stream>>>(x1, ln2_g, ln2_b, h2b);
    // 6. act = gelu(h2 @ w_fc + b_fc) -> bf16 (into qkv region; qkv dead)
    mgemm<EPI_BIAS_GELU_BF16><<<dim3(4 * CC / 128, NT / 128), 256, 0, stream>>>(
        h2b, wt_fc, b_fc, nullptr, nullptr, act, NT, 4 * CC, CC);
    // 7. out = act @ w_fc2 + b_fc2 + x1
    mgemm<EPI_BIAS_RES_F32><<<dim3(CC / 128, NT / 128), 256, 0, stream>>>(
        act, wt_fc2, b_fc2, x1, out, nullptr, NT, CC, 4 * CC);
}

// Round 3
// 558.530 us; speedup vs baseline: 13.5402x; 1.4050x over previous
//
#include <hip/hip_runtime.h>
#include <math.h>
#include <stdint.h>

#define BB 16
#define TT 512
#define CC 1024
#define HH 16
#define HD 64
#define NT (BB*TT)   // 8192 rows

typedef __bf16 bf16x8 __attribute__((ext_vector_type(8)));
typedef float f32x4 __attribute__((ext_vector_type(4)));

__device__ __forceinline__ unsigned short f2bf(float x) {
    union { float f; unsigned u; } v; v.f = x;
    unsigned r = v.u + 0x7fffu + ((v.u >> 16) & 1u);
    return (unsigned short)(r >> 16);
}

__device__ __forceinline__ void gload_lds16(const void* g, void* l) {
    __builtin_amdgcn_global_load_lds((const __attribute__((address_space(1))) uint32_t*)g,
                                     (__attribute__((address_space(3))) uint32_t*)l, 16, 0, 0);
}

// ---------------- weight transpose+convert: in[K,N] fp32 -> out[N,K] bf16 ----------------
__global__ __launch_bounds__(256) void tcvt_kernel(const float* __restrict__ in,
                                                   unsigned short* __restrict__ out,
                                                   int K, int N) {
    __shared__ float Tt[32][33];
    int n0 = blockIdx.x * 32, k0 = blockIdx.y * 32;
    int t = threadIdx.x;
#pragma unroll
    for (int i = 0; i < 4; i++) {
        int idx = i * 256 + t; int r = idx >> 5, c = idx & 31;
        Tt[r][c] = in[(size_t)(k0 + r) * N + n0 + c];
    }
    __syncthreads();
#pragma unroll
    for (int i = 0; i < 4; i++) {
        int idx = i * 256 + t; int r = idx >> 5, c = idx & 31; // r=n-local, c=k-local
        out[(size_t)(n0 + r) * K + k0 + c] = f2bf(Tt[c][r]);
    }
}

// ---------------- LayerNorm -> bf16 out ----------------
__global__ __launch_bounds__(256) void ln_kernel(const float* __restrict__ x,
                                                 const float* __restrict__ g,
                                                 const float* __restrict__ b,
                                                 unsigned short* __restrict__ out) {
    int row = blockIdx.x;
    const float* xr = x + (size_t)row * CC;
    unsigned short* orow = out + (size_t)row * CC;
    int tid = threadIdx.x;
    float v[4];
    float lsum = 0.f, lsq = 0.f;
#pragma unroll
    for (int i = 0; i < 4; i++) {
        v[i] = xr[tid + 256 * i];
        lsum += v[i];
        lsq  += v[i] * v[i];
    }
    __shared__ float ssum[4], ssq[4];
#pragma unroll
    for (int o = 32; o > 0; o >>= 1) {
        lsum += __shfl_down(lsum, o);
        lsq  += __shfl_down(lsq, o);
    }
    int wid = tid >> 6, lane = tid & 63;
    if (lane == 0) { ssum[wid] = lsum; ssq[wid] = lsq; }
    __syncthreads();
    if (tid == 0) {
        float s = 0.f, q = 0.f;
#pragma unroll
        for (int i = 0; i < 4; i++) { s += ssum[i]; q += ssq[i]; }
        float mu = s / CC;
        float var = q / CC - mu * mu;
        ssum[0] = mu;
        ssq[0] = rsqrtf(var + 1e-5f);
    }
    __syncthreads();
    float mu = ssum[0], rstd = ssq[0];
#pragma unroll
    for (int i = 0; i < 4; i++) {
        int c = tid + 256 * i;
        orow[c] = f2bf((v[i] - mu) * rstd * g[c] + b[c]);
    }
}

// ---------------- bf16 MFMA GEMM: C[M,N] = A[M,K](bf16) @ Bt[N,K](bf16)^T + epilogue ------
enum { EPI_BIAS_RES_F32 = 1, EPI_BIAS_GELU_BF16 = 2, EPI_QKV = 3 };

template <int EPI>
__global__ __launch_bounds__(256) void mgemm(const unsigned short* __restrict__ A,
                                             const unsigned short* __restrict__ Bt,
                                             const float* __restrict__ bias,
                                             const float* __restrict__ R,
                                             float* __restrict__ Cf,
                                             unsigned short* __restrict__ Cb,
                                             unsigned short* __restrict__ Vb,
                                             int M, int N, int K) {
    __shared__ __align__(16) unsigned short As[128 * 32];
    __shared__ __align__(16) unsigned short Bs[128 * 32];
    int tid = threadIdx.x;
    int w = tid >> 6, lane = tid & 63;
    int bm = blockIdx.y * 128, bn = blockIdx.x * 128;
    int wr = (w >> 1) * 64, wc = (w & 1) * 64;

    const unsigned short* gA0 = A + (size_t)(bm + (tid >> 2)) * K + (tid & 3) * 8;
    const unsigned short* gA1 = A + (size_t)(bm + 64 + (tid >> 2)) * K + (tid & 3) * 8;
    const unsigned short* gB0 = Bt + (size_t)(bn + (tid >> 2)) * K + (tid & 3) * 8;
    const unsigned short* gB1 = Bt + (size_t)(bn + 64 + (tid >> 2)) * K + (tid & 3) * 8;
    char* lA0 = (char*)As + w * 1024;
    char* lA1 = (char*)As + 4096 + w * 1024;
    char* lB0 = (char*)Bs + w * 1024;
    char* lB1 = (char*)Bs + 4096 + w * 1024;

    int ml = lane & 15, quad = lane >> 4;
    const bf16x8* As8 = (const bf16x8*)As;
    const bf16x8* Bs8 = (const bf16x8*)Bs;
    const bf16x8* pa = As8 + (wr + ml) * 4 + quad;
    const bf16x8* pb = Bs8 + (wc + ml) * 4 + quad;

    f32x4 acc[4][4] = {};

    for (int k0 = 0; k0 < K; k0 += 32) {
        gload_lds16(gA0 + k0, lA0);
        gload_lds16(gA1 + k0, lA1);
        gload_lds16(gB0 + k0, lB0);
        gload_lds16(gB1 + k0, lB1);
        __syncthreads();
        bf16x8 a[4], bb[4];
#pragma unroll
        for (int ti = 0; ti < 4; ti++) a[ti] = pa[ti * 64];
#pragma unroll
        for (int tj = 0; tj < 4; tj++) bb[tj] = pb[tj * 64];
#pragma unroll
        for (int ti = 0; ti < 4; ti++)
#pragma unroll
            for (int tj = 0; tj < 4; tj++)
                acc[ti][tj] = __builtin_amdgcn_mfma_f32_16x16x32_bf16(a[ti], bb[tj], acc[ti][tj], 0, 0, 0);
        __syncthreads();
    }

    // epilogue: D[m][n]: n = lane&15 (col), m = quad*4 + reg
#pragma unroll
    for (int ti = 0; ti < 4; ti++) {
#pragma unroll
        for (int tj = 0; tj < 4; tj++) {
            int n = bn + wc + tj * 16 + ml;
            int mbase = bm + wr + ti * 16 + quad * 4;
            float bv = bias[n];
            if (EPI == EPI_QKV && n >= 2 * CC) {
                // V: write transposed per-head: vt[b][h][d][t], t=mbase..+3 contiguous
                int d = n & (HD - 1), hh = (n - 2 * CC) >> 6;
                int tok = mbase & (TT - 1), bi = mbase >> 9;
                ushort4 pk;
                pk.x = f2bf(acc[ti][tj][0] + bv);
                pk.y = f2bf(acc[ti][tj][1] + bv);
                pk.z = f2bf(acc[ti][tj][2] + bv);
                pk.w = f2bf(acc[ti][tj][3] + bv);
                *(ushort4*)&Vb[((size_t)(bi * HH + hh) * HD + d) * TT + tok] = pk;
            } else {
#pragma unroll
                for (int reg = 0; reg < 4; reg++) {
                    int m = mbase + reg;
                    float v = acc[ti][tj][reg] + bv;
                    if (EPI == EPI_BIAS_GELU_BF16) {
                        float u = 0.7978845608028654f * (v + 0.044715f * v * v * v);
                        v = 0.5f * v * (1.0f + tanhf(u));
                        Cb[(size_t)m * N + n] = f2bf(v);
                    } else if (EPI == EPI_QKV) {
                        Cb[(size_t)m * N + n] = f2bf(v);   // Q,K region
                    } else {  // EPI_BIAS_RES_F32
                        v += R[(size_t)m * N + n];
                        Cf[(size_t)m * N + n] = v;
                    }
                }
            }
        }
    }
}

// ---------------- MFMA flash attention: block = (b,h,64-query tile), 4 waves x 16 q ------
// qkvb [B*T][3C] bf16 (Q at h*64, K at C+h*64); vt [B][H][HD][T] bf16; out yb [B*T][C] bf16
__global__ __launch_bounds__(256) void attn_kernel(const unsigned short* __restrict__ qkvb,
                                                   const unsigned short* __restrict__ vt,
                                                   const int* __restrict__ mask,
                                                   unsigned short* __restrict__ yb) {
    __shared__ __align__(16) unsigned short Qs[64][72];
    __shared__ __align__(16) unsigned short Ks[64][72];
    __shared__ __align__(16) unsigned short Vs[64][72];   // Vs[d][key]
    __shared__ __align__(16) unsigned short Ps[4][16][72];
    __shared__ int ms[64];
    int qt = blockIdx.x, h = blockIdx.y, b = blockIdx.z;
    int tid = threadIdx.x;
    int w = tid >> 6, lane = tid & 63, ml = lane & 15, quad = lane >> 4;

    const size_t row3 = 3 * CC;
    const unsigned short* qbase = qkvb + (size_t)(b * TT + qt * 64) * row3 + h * HD;
    const unsigned short* kbase = qkvb + (size_t)(b * TT) * row3 + CC + h * HD;
    const unsigned short* vbase = vt + (size_t)(b * HH + h) * HD * TT;

    // stage Q once: 64 rows x 8 chunks of 8 bf16
#pragma unroll
    for (int i = 0; i < 2; i++) {
        int c = i * 256 + tid; int r = c >> 3, c8 = c & 7;
        *(uint4*)&Qs[r][c8 * 8] = *(const uint4*)(qbase + (size_t)r * row3 + c8 * 8);
    }

    f32x4 o[4] = {};           // o[tj][reg]: row=quad*4+reg, col(d)=tj*16+ml
    float m_i[4], l_i[4];
#pragma unroll
    for (int r = 0; r < 4; r++) { m_i[r] = -1e30f; l_i[r] = 0.f; }

    for (int k0 = 0; k0 < TT; k0 += 64) {
#pragma unroll
        for (int i = 0; i < 2; i++) {
            int c = i * 256 + tid; int r = c >> 3, c8 = c & 7;
            *(uint4*)&Ks[r][c8 * 8] = *(const uint4*)(kbase + (size_t)(k0 + r) * row3 + c8 * 8);
            *(uint4*)&Vs[r][c8 * 8] = *(const uint4*)(vbase + (size_t)r * TT + k0 + c8 * 8);
        }
        if (tid < 64) ms[tid] = mask[b * TT + k0 + tid];
        __syncthreads();

        // S = Q K^T  (16q x 64keys per wave)
        bf16x8 aq0 = *(const bf16x8*)&Qs[w * 16 + ml][quad * 8];
        bf16x8 aq1 = *(const bf16x8*)&Qs[w * 16 + ml][32 + quad * 8];
        float p[4][4];
        float mt[4] = {-1e30f, -1e30f, -1e30f, -1e30f};
#pragma unroll
        for (int tj = 0; tj < 4; tj++) {
            bf16x8 b0 = *(const bf16x8*)&Ks[tj * 16 + ml][quad * 8];
            bf16x8 b1 = *(const bf16x8*)&Ks[tj * 16 + ml][32 + quad * 8];
            f32x4 z = {};
            z = __builtin_amdgcn_mfma_f32_16x16x32_bf16(aq0, b0, z, 0, 0, 0);
            z = __builtin_amdgcn_mfma_f32_16x16x32_bf16(aq1, b1, z, 0, 0, 0);
            bool dead = (ms[tj * 16 + ml] == 0);
#pragma unroll
            for (int r = 0; r < 4; r++) {
                float v = dead ? -1e30f : z[r] * 0.125f;
                p[tj][r] = v;
                mt[r] = fmaxf(mt[r], v);
            }
        }
#pragma unroll
        for (int off = 1; off < 16; off <<= 1)
#pragma unroll
            for (int r = 0; r < 4; r++) mt[r] = fmaxf(mt[r], __shfl_xor(mt[r], off));
        float alpha[4], rs[4];
#pragma unroll
        for (int r = 0; r < 4; r++) {
            float mn = fmaxf(m_i[r], mt[r]);
            alpha[r] = __expf(m_i[r] - mn);
            m_i[r] = mn;
            rs[r] = 0.f;
#pragma unroll
            for (int tj = 0; tj < 4; tj++) {
                float e = __expf(p[tj][r] - mn);
                p[tj][r] = e;
                rs[r] += e;
            }
        }
#pragma unroll
        for (int off = 1; off < 16; off <<= 1)
#pragma unroll
            for (int r = 0; r < 4; r++) rs[r] += __shfl_xor(rs[r], off);
#pragma unroll
        for (int r = 0; r < 4; r++) {
            l_i[r] = l_i[r] * alpha[r] + rs[r];
#pragma unroll
            for (int tj = 0; tj < 4; tj++) o[tj][r] *= alpha[r];
        }
        // P (C-layout) -> LDS bf16 -> A-layout frags  (wave-private strip, no barrier)
#pragma unroll
        for (int tj = 0; tj < 4; tj++)
#pragma unroll
            for (int r = 0; r < 4; r++)
                Ps[w][quad * 4 + r][tj * 16 + ml] = f2bf(p[tj][r]);
        bf16x8 pa0 = *(const bf16x8*)&Ps[w][ml][quad * 8];
        bf16x8 pa1 = *(const bf16x8*)&Ps[w][ml][32 + quad * 8];
#pragma unroll
        for (int tj = 0; tj < 4; tj++) {
            bf16x8 v0 = *(const bf16x8*)&Vs[tj * 16 + ml][quad * 8];
            bf16x8 v1 = *(const bf16x8*)&Vs[tj * 16 + ml][32 + quad * 8];
            o[tj] = __builtin_amdgcn_mfma_f32_16x16x32_bf16(pa0, v0, o[tj], 0, 0, 0);
            o[tj] = __builtin_amdgcn_mfma_f32_16x16x32_bf16(pa1, v1, o[tj], 0, 0, 0);
        }
        __syncthreads();
    }

    // epilogue: q = qt*64 + w*16 + quad*4+r, d = tj*16+ml
#pragma unroll
    for (int r = 0; r < 4; r++) {
        float inv = 1.f / l_i[r];
        int q = qt * 64 + w * 16 + quad * 4 + r;
        unsigned short* yr = yb + (size_t)(b * TT + q) * CC + h * HD;
#pragma unroll
        for (int tj = 0; tj < 4; tj++)
            yr[tj * 16 + ml] = f2bf(o[tj][r] * inv);
    }
}

extern "C" void kernel_launch(void* const* d_in, const int* in_sizes, int n_in,
                              void* d_out, int out_size, void* d_ws, size_t ws_size,
                              hipStream_t stream) {
    const float* x      = (const float*)d_in[0];
    const int*   mask   = (const int*)d_in[1];
    const float* ln1_g  = (const float*)d_in[2];
    const float* ln1_b  = (const float*)d_in[3];
    const float* w_attn = (const float*)d_in[4];
    const float* b_attn = (const float*)d_in[5];
    const float* w_o    = (const float*)d_in[6];
    const float* b_o    = (const float*)d_in[7];
    const float* ln2_g  = (const float*)d_in[8];
    const float* ln2_b  = (const float*)d_in[9];
    const float* w_fc   = (const float*)d_in[10];
    const float* b_fc   = (const float*)d_in[11];
    const float* w_fc2  = (const float*)d_in[12];
    const float* b_fc2  = (const float*)d_in[13];
    float* out = (float*)d_out;

    char* ws = (char*)d_ws;
    size_t off = 0;
    unsigned short* wt_attn = (unsigned short*)(ws + off); off += (size_t)3 * CC * CC * 2;  // 6MB
    unsigned short* wt_o    = (unsigned short*)(ws + off); off += (size_t)CC * CC * 2;      // 2MB
    unsigned short* wt_fc   = (unsigned short*)(ws + off); off += (size_t)4 * CC * CC * 2;  // 8MB
    unsigned short* wt_fc2  = (unsigned short*)(ws + off); off += (size_t)4 * CC * CC * 2;  // 8MB
    // region1 (64MB): qkvb(48) + vt(16), reused as act(64) after attention
    unsigned short* qkvb    = (unsigned short*)(ws + off);
    unsigned short* act     = (unsigned short*)(ws + off); off += (size_t)NT * 3 * CC * 2;
    unsigned short* vt      = (unsigned short*)(ws + off); off += (size_t)BB * CC * TT * 2 / 1; // B*H*HD*T = 16*1024*512
    unsigned short* hb      = (unsigned short*)(ws + off);                                   // 16MB, reused as yb
    unsigned short* yb      = (unsigned short*)(ws + off); off += (size_t)NT * CC * 2;
    float* x1               = (float*)(ws + off); off += (size_t)NT * CC * 4;                // 32MB
    unsigned short* h2b     = (unsigned short*)(ws + off); off += (size_t)NT * CC * 2;       // 16MB

    // weight transpose+convert: W[K,N] f32 -> Wt[N,K] bf16
    tcvt_kernel<<<dim3(3 * CC / 32, CC / 32), 256, 0, stream>>>(w_attn, wt_attn, CC, 3 * CC);
    tcvt_kernel<<<dim3(CC / 32, CC / 32), 256, 0, stream>>>(w_o, wt_o, CC, CC);
    tcvt_kernel<<<dim3(4 * CC / 32, CC / 32), 256, 0, stream>>>(w_fc, wt_fc, CC, 4 * CC);
    tcvt_kernel<<<dim3(CC / 32, 4 * CC / 32), 256, 0, stream>>>(w_fc2, wt_fc2, 4 * CC, CC);

    // 1. LN1 -> bf16
    ln_kernel<<<NT, 256, 0, stream>>>(x, ln1_g, ln1_b, hb);
    // 2. qkv GEMM -> Q,K bf16 [B*T,3C] + V transposed vt[b][h][d][t]
    mgemm<EPI_QKV><<<dim3(3 * CC / 128, NT / 128), 256, 0, stream>>>(
        hb, wt_attn, b_attn, nullptr, nullptr, qkvb, vt, NT, 3 * CC, CC);
    // 3. MFMA flash attention -> yb bf16
    attn_kernel<<<dim3(TT / 64, HH, BB), 256, 0, stream>>>(qkvb, vt, mask, yb);
    // 4. x1 = y @ w_o + b_o + x
    mgemm<EPI_BIAS_RES_F32><<<dim3(CC / 128, NT / 128), 256, 0, stream>>>(
        yb, wt_o, b_o, x, x1, nullptr, nullptr, NT, CC, CC);
    // 5. LN2 -> bf16
    ln_kernel<<<NT, 256, 0, stream>>>(x1, ln2_g, ln2_b, h2b);
    // 6. act = gelu(h2 @ w_fc + b_fc) -> bf16 (into region1; qkvb/vt dead)
    mgemm<EPI_BIAS_GELU_BF16><<<dim3(4 * CC / 128, NT / 128), 256, 0, stream>>>(
        h2b, wt_fc, b_fc, nullptr, nullptr, act, nullptr, NT, 4 * CC, CC);
    // 7. out = act @ w_fc2 + b_fc2 + x1
    mgemm<EPI_BIAS_RES_F32><<<dim3(CC / 128, NT / 128), 256, 0, stream>>>(
        act, wt_fc2, b_fc2, x1, out, nullptr, nullptr, NT, CC, 4 * CC);
}

// Round 4
// 545.610 us; speedup vs baseline: 13.8609x; 1.0237x over previous
//
#include <hip/hip_runtime.h>
#include <math.h>
#include <stdint.h>

#define BB 16
#define TT 512
#define CC 1024
#define HH 16
#define HD 64
#define NT (BB*TT)   // 8192 rows

typedef __bf16 bf16x8 __attribute__((ext_vector_type(8)));
typedef float f32x4 __attribute__((ext_vector_type(4)));

__device__ __forceinline__ unsigned short f2bf(float x) {
    union { float f; unsigned u; } v; v.f = x;
    unsigned r = v.u + 0x7fffu + ((v.u >> 16) & 1u);
    return (unsigned short)(r >> 16);
}

__device__ __forceinline__ void gload_lds16(const void* g, void* l) {
    __builtin_amdgcn_global_load_lds((const __attribute__((address_space(1))) uint32_t*)g,
                                     (__attribute__((address_space(3))) uint32_t*)l, 16, 0, 0);
}

// ---------------- weight transpose+convert: in[K,N] fp32 -> out[N,K] bf16 ----------------
__global__ __launch_bounds__(256) void tcvt_kernel(const float* __restrict__ in,
                                                   unsigned short* __restrict__ out,
                                                   int K, int N) {
    __shared__ float Tt[32][33];
    int n0 = blockIdx.x * 32, k0 = blockIdx.y * 32;
    int t = threadIdx.x;
#pragma unroll
    for (int i = 0; i < 4; i++) {
        int idx = i * 256 + t; int r = idx >> 5, c = idx & 31;
        Tt[r][c] = in[(size_t)(k0 + r) * N + n0 + c];
    }
    __syncthreads();
#pragma unroll
    for (int i = 0; i < 4; i++) {
        int idx = i * 256 + t; int r = idx >> 5, c = idx & 31; // r=n-local, c=k-local
        out[(size_t)(n0 + r) * K + k0 + c] = f2bf(Tt[c][r]);
    }
}

// ---------------- LayerNorm -> bf16 out ----------------
__global__ __launch_bounds__(256) void ln_kernel(const float* __restrict__ x,
                                                 const float* __restrict__ g,
                                                 const float* __restrict__ b,
                                                 unsigned short* __restrict__ out) {
    int row = blockIdx.x;
    const float* xr = x + (size_t)row * CC;
    unsigned short* orow = out + (size_t)row * CC;
    int tid = threadIdx.x;
    float v[4];
    float lsum = 0.f, lsq = 0.f;
#pragma unroll
    for (int i = 0; i < 4; i++) {
        v[i] = xr[tid + 256 * i];
        lsum += v[i];
        lsq  += v[i] * v[i];
    }
    __shared__ float ssum[4], ssq[4];
#pragma unroll
    for (int o = 32; o > 0; o >>= 1) {
        lsum += __shfl_down(lsum, o);
        lsq  += __shfl_down(lsq, o);
    }
    int wid = tid >> 6, lane = tid & 63;
    if (lane == 0) { ssum[wid] = lsum; ssq[wid] = lsq; }
    __syncthreads();
    if (tid == 0) {
        float s = 0.f, q = 0.f;
#pragma unroll
        for (int i = 0; i < 4; i++) { s += ssum[i]; q += ssq[i]; }
        float mu = s / CC;
        float var = q / CC - mu * mu;
        ssum[0] = mu;
        ssq[0] = rsqrtf(var + 1e-5f);
    }
    __syncthreads();
    float mu = ssum[0], rstd = ssq[0];
#pragma unroll
    for (int i = 0; i < 4; i++) {
        int c = tid + 256 * i;
        orow[c] = f2bf((v[i] - mu) * rstd * g[c] + b[c]);
    }
}

// ---------------- bf16 MFMA GEMM: C[M,N] = A[M,K](bf16) @ Bt[N,K](bf16)^T + epilogue ------
// LDS XOR-swizzle: LDS slot (row, c) holds global k-chunk c ^ ((row>>1)&3).
// Staging swizzles the GLOBAL source (global_load_lds dest is lane-linear);
// readers pick slot quad ^ ((ml>>1)&3) -> every 16-lane phase is 2-way/free.
enum { EPI_BIAS_RES_F32 = 1, EPI_BIAS_GELU_BF16 = 2, EPI_QKV = 3 };

template <int EPI>
__global__ __launch_bounds__(256) void mgemm(const unsigned short* __restrict__ A,
                                             const unsigned short* __restrict__ Bt,
                                             const float* __restrict__ bias,
                                             const float* __restrict__ R,
                                             float* __restrict__ Cf,
                                             unsigned short* __restrict__ Cb,
                                             unsigned short* __restrict__ Vb,
                                             int M, int N, int K) {
    __shared__ __align__(16) unsigned short As[128 * 32];
    __shared__ __align__(16) unsigned short Bs[128 * 32];
    int tid = threadIdx.x;
    int w = tid >> 6, lane = tid & 63;
    int bm = blockIdx.y * 128, bn = blockIdx.x * 128;
    int wr = (w >> 1) * 64, wc = (w & 1) * 64;

    // swizzled k-chunk for the staging fetch
    int kswz = ((tid & 3) ^ ((tid >> 3) & 3)) * 8;
    const unsigned short* gA0 = A + (size_t)(bm + (tid >> 2)) * K + kswz;
    const unsigned short* gA1 = A + (size_t)(bm + 64 + (tid >> 2)) * K + kswz;
    const unsigned short* gB0 = Bt + (size_t)(bn + (tid >> 2)) * K + kswz;
    const unsigned short* gB1 = Bt + (size_t)(bn + 64 + (tid >> 2)) * K + kswz;
    char* lA0 = (char*)As + w * 1024;
    char* lA1 = (char*)As + 4096 + w * 1024;
    char* lB0 = (char*)Bs + w * 1024;
    char* lB1 = (char*)Bs + 4096 + w * 1024;

    int ml = lane & 15, quad = lane >> 4;
    int rswz = quad ^ ((ml >> 1) & 3);
    const bf16x8* As8 = (const bf16x8*)As;
    const bf16x8* Bs8 = (const bf16x8*)Bs;
    const bf16x8* pa = As8 + (wr + ml) * 4 + rswz;
    const bf16x8* pb = Bs8 + (wc + ml) * 4 + rswz;

    f32x4 acc[4][4] = {};

    for (int k0 = 0; k0 < K; k0 += 32) {
        gload_lds16(gA0 + k0, lA0);
        gload_lds16(gA1 + k0, lA1);
        gload_lds16(gB0 + k0, lB0);
        gload_lds16(gB1 + k0, lB1);
        __syncthreads();
        bf16x8 a[4], bb[4];
#pragma unroll
        for (int ti = 0; ti < 4; ti++) a[ti] = pa[ti * 64];
#pragma unroll
        for (int tj = 0; tj < 4; tj++) bb[tj] = pb[tj * 64];
#pragma unroll
        for (int ti = 0; ti < 4; ti++)
#pragma unroll
            for (int tj = 0; tj < 4; tj++)
                acc[ti][tj] = __builtin_amdgcn_mfma_f32_16x16x32_bf16(a[ti], bb[tj], acc[ti][tj], 0, 0, 0);
        __syncthreads();
    }

    // epilogue: D[m][n]: n = lane&15 (col), m = quad*4 + reg
#pragma unroll
    for (int ti = 0; ti < 4; ti++) {
#pragma unroll
        for (int tj = 0; tj < 4; tj++) {
            int n = bn + wc + tj * 16 + ml;
            int mbase = bm + wr + ti * 16 + quad * 4;
            float bv = bias[n];
            if (EPI == EPI_QKV && n >= 2 * CC) {
                // V: write transposed per-head: vt[b][h][d][t], t=mbase..+3 contiguous
                int d = n & (HD - 1), hh = (n - 2 * CC) >> 6;
                int tok = mbase & (TT - 1), bi = mbase >> 9;
                ushort4 pk;
                pk.x = f2bf(acc[ti][tj][0] + bv);
                pk.y = f2bf(acc[ti][tj][1] + bv);
                pk.z = f2bf(acc[ti][tj][2] + bv);
                pk.w = f2bf(acc[ti][tj][3] + bv);
                *(ushort4*)&Vb[((size_t)(bi * HH + hh) * HD + d) * TT + tok] = pk;
            } else {
#pragma unroll
                for (int reg = 0; reg < 4; reg++) {
                    int m = mbase + reg;
                    float v = acc[ti][tj][reg] + bv;
                    if (EPI == EPI_BIAS_GELU_BF16) {
                        // gelu(v) = v * sigmoid(2u), 2u = 2*0.79788456*(v + 0.044715 v^3)
                        float u2 = 1.5957691216057308f * (v + 0.044715f * v * v * v);
                        v = v / (1.0f + __expf(-u2));
                        Cb[(size_t)m * N + n] = f2bf(v);
                    } else if (EPI == EPI_QKV) {
                        Cb[(size_t)m * N + n] = f2bf(v);   // Q,K region
                    } else {  // EPI_BIAS_RES_F32
                        v += R[(size_t)m * N + n];
                        Cf[(size_t)m * N + n] = v;
                    }
                }
            }
        }
    }
}

// ---------------- MFMA flash attention: block = (b,h,64-query tile), 4 waves x 16 q ------
// qkvb [B*T][3C] bf16 (Q at h*64, K at C+h*64); vt [B][H][HD][T] bf16; out yb [B*T][C] bf16
__global__ __launch_bounds__(256) void attn_kernel(const unsigned short* __restrict__ qkvb,
                                                   const unsigned short* __restrict__ vt,
                                                   const int* __restrict__ mask,
                                                   unsigned short* __restrict__ yb) {
    __shared__ __align__(16) unsigned short Qs[64][72];
    __shared__ __align__(16) unsigned short Ks[64][72];
    __shared__ __align__(16) unsigned short Vs[64][72];   // Vs[d][key]
    __shared__ __align__(16) unsigned short Ps[4][16][72];
    __shared__ int ms[64];
    int qt = blockIdx.x, h = blockIdx.y, b = blockIdx.z;
    int tid = threadIdx.x;
    int w = tid >> 6, lane = tid & 63, ml = lane & 15, quad = lane >> 4;

    const size_t row3 = 3 * CC;
    const unsigned short* qbase = qkvb + (size_t)(b * TT + qt * 64) * row3 + h * HD;
    const unsigned short* kbase = qkvb + (size_t)(b * TT) * row3 + CC + h * HD;
    const unsigned short* vbase = vt + (size_t)(b * HH + h) * HD * TT;

    // stage Q once: 64 rows x 8 chunks of 8 bf16
#pragma unroll
    for (int i = 0; i < 2; i++) {
        int c = i * 256 + tid; int r = c >> 3, c8 = c & 7;
        *(uint4*)&Qs[r][c8 * 8] = *(const uint4*)(qbase + (size_t)r * row3 + c8 * 8);
    }

    f32x4 o[4] = {};           // o[tj][reg]: row=quad*4+reg, col(d)=tj*16+ml
    float m_i[4], l_i[4];
#pragma unroll
    for (int r = 0; r < 4; r++) { m_i[r] = -1e30f; l_i[r] = 0.f; }

    for (int k0 = 0; k0 < TT; k0 += 64) {
#pragma unroll
        for (int i = 0; i < 2; i++) {
            int c = i * 256 + tid; int r = c >> 3, c8 = c & 7;
            *(uint4*)&Ks[r][c8 * 8] = *(const uint4*)(kbase + (size_t)(k0 + r) * row3 + c8 * 8);
            *(uint4*)&Vs[r][c8 * 8] = *(const uint4*)(vbase + (size_t)r * TT + k0 + c8 * 8);
        }
        if (tid < 64) ms[tid] = mask[b * TT + k0 + tid];
        __syncthreads();

        // S = Q K^T  (16q x 64keys per wave)
        bf16x8 aq0 = *(const bf16x8*)&Qs[w * 16 + ml][quad * 8];
        bf16x8 aq1 = *(const bf16x8*)&Qs[w * 16 + ml][32 + quad * 8];
        float p[4][4];
        float mt[4] = {-1e30f, -1e30f, -1e30f, -1e30f};
#pragma unroll
        for (int tj = 0; tj < 4; tj++) {
            bf16x8 b0 = *(const bf16x8*)&Ks[tj * 16 + ml][quad * 8];
            bf16x8 b1 = *(const bf16x8*)&Ks[tj * 16 + ml][32 + quad * 8];
            f32x4 z = {};
            z = __builtin_amdgcn_mfma_f32_16x16x32_bf16(aq0, b0, z, 0, 0, 0);
            z = __builtin_amdgcn_mfma_f32_16x16x32_bf16(aq1, b1, z, 0, 0, 0);
            bool dead = (ms[tj * 16 + ml] == 0);
#pragma unroll
            for (int r = 0; r < 4; r++) {
                float v = dead ? -1e30f : z[r] * 0.125f;
                p[tj][r] = v;
                mt[r] = fmaxf(mt[r], v);
            }
        }
#pragma unroll
        for (int off = 1; off < 16; off <<= 1)
#pragma unroll
            for (int r = 0; r < 4; r++) mt[r] = fmaxf(mt[r], __shfl_xor(mt[r], off));
        float alpha[4], rs[4];
#pragma unroll
        for (int r = 0; r < 4; r++) {
            float mn = fmaxf(m_i[r], mt[r]);
            alpha[r] = __expf(m_i[r] - mn);
            m_i[r] = mn;
            rs[r] = 0.f;
#pragma unroll
            for (int tj = 0; tj < 4; tj++) {
                float e = __expf(p[tj][r] - mn);
                p[tj][r] = e;
                rs[r] += e;
            }
        }
#pragma unroll
        for (int off = 1; off < 16; off <<= 1)
#pragma unroll
            for (int r = 0; r < 4; r++) rs[r] += __shfl_xor(rs[r], off);
#pragma unroll
        for (int r = 0; r < 4; r++) {
            l_i[r] = l_i[r] * alpha[r] + rs[r];
#pragma unroll
            for (int tj = 0; tj < 4; tj++) o[tj][r] *= alpha[r];
        }
        // P (C-layout) -> LDS bf16 -> A-layout frags  (wave-private strip, no barrier)
#pragma unroll
        for (int tj = 0; tj < 4; tj++)
#pragma unroll
            for (int r = 0; r < 4; r++)
                Ps[w][quad * 4 + r][tj * 16 + ml] = f2bf(p[tj][r]);
        bf16x8 pa0 = *(const bf16x8*)&Ps[w][ml][quad * 8];
        bf16x8 pa1 = *(const bf16x8*)&Ps[w][ml][32 + quad * 8];
#pragma unroll
        for (int tj = 0; tj < 4; tj++) {
            bf16x8 v0 = *(const bf16x8*)&Vs[tj * 16 + ml][quad * 8];
            bf16x8 v1 = *(const bf16x8*)&Vs[tj * 16 + ml][32 + quad * 8];
            o[tj] = __builtin_amdgcn_mfma_f32_16x16x32_bf16(pa0, v0, o[tj], 0, 0, 0);
            o[tj] = __builtin_amdgcn_mfma_f32_16x16x32_bf16(pa1, v1, o[tj], 0, 0, 0);
        }
        __syncthreads();
    }

    // epilogue: q = qt*64 + w*16 + quad*4+r, d = tj*16+ml
#pragma unroll
    for (int r = 0; r < 4; r++) {
        float inv = 1.f / l_i[r];
        int q = qt * 64 + w * 16 + quad * 4 + r;
        unsigned short* yr = yb + (size_t)(b * TT + q) * CC + h * HD;
#pragma unroll
        for (int tj = 0; tj < 4; tj++)
            yr[tj * 16 + ml] = f2bf(o[tj][r] * inv);
    }
}

extern "C" void kernel_launch(void* const* d_in, const int* in_sizes, int n_in,
                              void* d_out, int out_size, void* d_ws, size_t ws_size,
                              hipStream_t stream) {
    const float* x      = (const float*)d_in[0];
    const int*   mask   = (const int*)d_in[1];
    const float* ln1_g  = (const float*)d_in[2];
    const float* ln1_b  = (const float*)d_in[3];
    const float* w_attn = (const float*)d_in[4];
    const float* b_attn = (const float*)d_in[5];
    const float* w_o    = (const float*)d_in[6];
    const float* b_o    = (const float*)d_in[7];
    const float* ln2_g  = (const float*)d_in[8];
    const float* ln2_b  = (const float*)d_in[9];
    const float* w_fc   = (const float*)d_in[10];
    const float* b_fc   = (const float*)d_in[11];
    const float* w_fc2  = (const float*)d_in[12];
    const float* b_fc2  = (const float*)d_in[13];
    float* out = (float*)d_out;

    char* ws = (char*)d_ws;
    size_t off = 0;
    unsigned short* wt_attn = (unsigned short*)(ws + off); off += (size_t)3 * CC * CC * 2;  // 6MB
    unsigned short* wt_o    = (unsigned short*)(ws + off); off += (size_t)CC * CC * 2;      // 2MB
    unsigned short* wt_fc   = (unsigned short*)(ws + off); off += (size_t)4 * CC * CC * 2;  // 8MB
    unsigned short* wt_fc2  = (unsigned short*)(ws + off); off += (size_t)4 * CC * CC * 2;  // 8MB
    // region1 (64MB): qkvb(48) + vt(16), reused as act(64) after attention
    unsigned short* qkvb    = (unsigned short*)(ws + off);
    unsigned short* act     = (unsigned short*)(ws + off); off += (size_t)NT * 3 * CC * 2;
    unsigned short* vt      = (unsigned short*)(ws + off); off += (size_t)BB * CC * TT * 2; // B*H*HD*T
    unsigned short* hb      = (unsigned short*)(ws + off);                                   // 16MB, reused as yb
    unsigned short* yb      = (unsigned short*)(ws + off); off += (size_t)NT * CC * 2;
    float* x1               = (float*)(ws + off); off += (size_t)NT * CC * 4;                // 32MB
    unsigned short* h2b     = (unsigned short*)(ws + off); off += (size_t)NT * CC * 2;       // 16MB

    // weight transpose+convert: W[K,N] f32 -> Wt[N,K] bf16
    tcvt_kernel<<<dim3(3 * CC / 32, CC / 32), 256, 0, stream>>>(w_attn, wt_attn, CC, 3 * CC);
    tcvt_kernel<<<dim3(CC / 32, CC / 32), 256, 0, stream>>>(w_o, wt_o, CC, CC);
    tcvt_kernel<<<dim3(4 * CC / 32, CC / 32), 256, 0, stream>>>(w_fc, wt_fc, CC, 4 * CC);
    tcvt_kernel<<<dim3(CC / 32, 4 * CC / 32), 256, 0, stream>>>(w_fc2, wt_fc2, 4 * CC, CC);

    // 1. LN1 -> bf16
    ln_kernel<<<NT, 256, 0, stream>>>(x, ln1_g, ln1_b, hb);
    // 2. qkv GEMM -> Q,K bf16 [B*T,3C] + V transposed vt[b][h][d][t]
    mgemm<EPI_QKV><<<dim3(3 * CC / 128, NT / 128), 256, 0, stream>>>(
        hb, wt_attn, b_attn, nullptr, nullptr, qkvb, vt, NT, 3 * CC, CC);
    // 3. MFMA flash attention -> yb bf16
    attn_kernel<<<dim3(TT / 64, HH, BB), 256, 0, stream>>>(qkvb, vt, mask, yb);
    // 4. x1 = y @ w_o + b_o + x
    mgemm<EPI_BIAS_RES_F32><<<dim3(CC / 128, NT / 128), 256, 0, stream>>>(
        yb, wt_o, b_o, x, x1, nullptr, nullptr, NT, CC, CC);
    // 5. LN2 -> bf16
    ln_kernel<<<NT, 256, 0, stream>>>(x1, ln2_g, ln2_b, h2b);
    // 6. act = gelu(h2 @ w_fc + b_fc) -> bf16 (into region1; qkvb/vt dead)
    mgemm<EPI_BIAS_GELU_BF16><<<dim3(4 * CC / 128, NT / 128), 256, 0, stream>>>(
        h2b, wt_fc, b_fc, nullptr, nullptr, act, nullptr, NT, 4 * CC, CC);
    // 7. out = act @ w_fc2 + b_fc2 + x1
    mgemm<EPI_BIAS_RES_F32><<<dim3(CC / 128, NT / 128), 256, 0, stream>>>(
        act, wt_fc2, b_fc2, x1, out, nullptr, nullptr, NT, CC, 4 * CC);
}

// Round 5
// 520.504 us; speedup vs baseline: 14.5294x; 1.0482x over previous
//
#include <hip/hip_runtime.h>
#include <math.h>
#include <stdint.h>

#define BB 16
#define TT 512
#define CC 1024
#define HH 16
#define HD 64
#define NT (BB*TT)   // 8192 rows

typedef __bf16 bf16x8 __attribute__((ext_vector_type(8)));
typedef float f32x4 __attribute__((ext_vector_type(4)));

__device__ __forceinline__ unsigned short f2bf(float x) {
    union { float f; unsigned u; } v; v.f = x;
    unsigned r = v.u + 0x7fffu + ((v.u >> 16) & 1u);
    return (unsigned short)(r >> 16);
}

__device__ __forceinline__ void gload_lds16(const void* g, void* l) {
    __builtin_amdgcn_global_load_lds((const __attribute__((address_space(1))) uint32_t*)g,
                                     (__attribute__((address_space(3))) uint32_t*)l, 16, 0, 0);
}

// ---------------- weight transpose+convert: in[K,N] fp32 -> out[N,K] bf16 ----------------
__global__ __launch_bounds__(256) void tcvt_kernel(const float* __restrict__ in,
                                                   unsigned short* __restrict__ out,
                                                   int K, int N) {
    __shared__ float Tt[32][33];
    int n0 = blockIdx.x * 32, k0 = blockIdx.y * 32;
    int t = threadIdx.x;
#pragma unroll
    for (int i = 0; i < 4; i++) {
        int idx = i * 256 + t; int r = idx >> 5, c = idx & 31;
        Tt[r][c] = in[(size_t)(k0 + r) * N + n0 + c];
    }
    __syncthreads();
#pragma unroll
    for (int i = 0; i < 4; i++) {
        int idx = i * 256 + t; int r = idx >> 5, c = idx & 31; // r=n-local, c=k-local
        out[(size_t)(n0 + r) * K + k0 + c] = f2bf(Tt[c][r]);
    }
}

// ---------------- LayerNorm -> bf16 out ----------------
__global__ __launch_bounds__(256) void ln_kernel(const float* __restrict__ x,
                                                 const float* __restrict__ g,
                                                 const float* __restrict__ b,
                                                 unsigned short* __restrict__ out) {
    int row = blockIdx.x;
    const float* xr = x + (size_t)row * CC;
    unsigned short* orow = out + (size_t)row * CC;
    int tid = threadIdx.x;
    float v[4];
    float lsum = 0.f, lsq = 0.f;
#pragma unroll
    for (int i = 0; i < 4; i++) {
        v[i] = xr[tid + 256 * i];
        lsum += v[i];
        lsq  += v[i] * v[i];
    }
    __shared__ float ssum[4], ssq[4];
#pragma unroll
    for (int o = 32; o > 0; o >>= 1) {
        lsum += __shfl_down(lsum, o);
        lsq  += __shfl_down(lsq, o);
    }
    int wid = tid >> 6, lane = tid & 63;
    if (lane == 0) { ssum[wid] = lsum; ssq[wid] = lsq; }
    __syncthreads();
    if (tid == 0) {
        float s = 0.f, q = 0.f;
#pragma unroll
        for (int i = 0; i < 4; i++) { s += ssum[i]; q += ssq[i]; }
        float mu = s / CC;
        float var = q / CC - mu * mu;
        ssum[0] = mu;
        ssq[0] = rsqrtf(var + 1e-5f);
    }
    __syncthreads();
    float mu = ssum[0], rstd = ssq[0];
#pragma unroll
    for (int i = 0; i < 4; i++) {
        int c = tid + 256 * i;
        orow[c] = f2bf((v[i] - mu) * rstd * g[c] + b[c]);
    }
}

// ---------------- bf16 MFMA GEMM: C[M,N] = A[M,K](bf16) @ Bt[N,K](bf16)^T + epilogue ------
// BK=64 (one barrier-pair per 64-K): As/Bs rows of 64 bf16 = 128B.
// XOR swizzle: LDS slot (row, c) holds global k-chunk c ^ (row&7); swizzle applied at the
// GLOBAL source (global_load_lds dest is lane-linear); readers pick slot (h*4+quad)^(ml&7)
// -> every 16-lane phase touches each bank 2-way (free).
// Supertile remap: groups of 8 M-tiles, N sweeps inside -> XCD-local A strips, shared B tile.
enum { EPI_BIAS_RES_F32 = 1, EPI_BIAS_GELU_BF16 = 2, EPI_QKV = 3 };

template <int EPI>
__global__ __launch_bounds__(256) void mgemm(const unsigned short* __restrict__ A,
                                             const unsigned short* __restrict__ Bt,
                                             const float* __restrict__ bias,
                                             const float* __restrict__ R,
                                             float* __restrict__ Cf,
                                             unsigned short* __restrict__ Cb,
                                             unsigned short* __restrict__ Vb,
                                             int M, int N, int K) {
    __shared__ __align__(16) unsigned short As[128 * 64];
    __shared__ __align__(16) unsigned short Bs[128 * 64];
    int tid = threadIdx.x;
    int w = tid >> 6, lane = tid & 63;

    // supertile remap (gridM always 64 here, divisible by 8)
    int bid = blockIdx.y * gridDim.x + blockIdx.x;
    int per = 8 * gridDim.x;
    int grp = bid / per, rem = bid % per;
    int bm = (grp * 8 + (rem & 7)) * 128;
    int bn = (rem >> 3) * 128;
    int wr = (w >> 1) * 64, wc = (w & 1) * 64;

    // staging: pass p covers rows p*32 + (tid>>3); chunk slot tid&7 holds global chunk
    // (tid&7) ^ ((tid>>3)&7); 8 consecutive tids cover one row's full 128B (coalesced).
    int row8 = tid >> 3;
    int kswz = ((tid & 7) ^ (row8 & 7)) * 8;
    const unsigned short* gA = A + (size_t)(bm + row8) * K + kswz;
    const unsigned short* gB = Bt + (size_t)(bn + row8) * K + kswz;
    char* lA = (char*)As + w * 1024;
    char* lB = (char*)Bs + w * 1024;

    int ml = lane & 15, quad = lane >> 4;
    int s0 = ((quad ^ (ml & 7))) * 8;        // k-half 0 slot (ushort offset)
    int s1 = (((quad + 4) ^ (ml & 7))) * 8;  // k-half 1
    const unsigned short* rowA = As + (size_t)(wr + ml) * 64;
    const unsigned short* rowB = Bs + (size_t)(wc + ml) * 64;

    f32x4 acc[4][4] = {};

    for (int k0 = 0; k0 < K; k0 += 64) {
#pragma unroll
        for (int p = 0; p < 4; p++) {
            gload_lds16(gA + (size_t)(p * 32) * K + k0, lA + p * 4096);
            gload_lds16(gB + (size_t)(p * 32) * K + k0, lB + p * 4096);
        }
        __syncthreads();
        {
            bf16x8 a[4], bb[4];
#pragma unroll
            for (int ti = 0; ti < 4; ti++) a[ti] = *(const bf16x8*)&rowA[ti * 1024 + s0];
#pragma unroll
            for (int tj = 0; tj < 4; tj++) bb[tj] = *(const bf16x8*)&rowB[tj * 1024 + s0];
#pragma unroll
            for (int ti = 0; ti < 4; ti++)
#pragma unroll
                for (int tj = 0; tj < 4; tj++)
                    acc[ti][tj] = __builtin_amdgcn_mfma_f32_16x16x32_bf16(a[ti], bb[tj], acc[ti][tj], 0, 0, 0);
        }
        {
            bf16x8 a[4], bb[4];
#pragma unroll
            for (int ti = 0; ti < 4; ti++) a[ti] = *(const bf16x8*)&rowA[ti * 1024 + s1];
#pragma unroll
            for (int tj = 0; tj < 4; tj++) bb[tj] = *(const bf16x8*)&rowB[tj * 1024 + s1];
#pragma unroll
            for (int ti = 0; ti < 4; ti++)
#pragma unroll
                for (int tj = 0; tj < 4; tj++)
                    acc[ti][tj] = __builtin_amdgcn_mfma_f32_16x16x32_bf16(a[ti], bb[tj], acc[ti][tj], 0, 0, 0);
        }
        __syncthreads();
    }

    // epilogue: D[m][n]: n = lane&15 (col), m = quad*4 + reg
#pragma unroll
    for (int ti = 0; ti < 4; ti++) {
#pragma unroll
        for (int tj = 0; tj < 4; tj++) {
            int n = bn + wc + tj * 16 + ml;
            int mbase = bm + wr + ti * 16 + quad * 4;
            float bv = bias[n];
            if (EPI == EPI_QKV && n >= 2 * CC) {
                // V: write transposed per-head: vt[b][h][d][t], t=mbase..+3 contiguous
                int d = n & (HD - 1), hh = (n - 2 * CC) >> 6;
                int tok = mbase & (TT - 1), bi = mbase >> 9;
                ushort4 pk;
                pk.x = f2bf(acc[ti][tj][0] + bv);
                pk.y = f2bf(acc[ti][tj][1] + bv);
                pk.z = f2bf(acc[ti][tj][2] + bv);
                pk.w = f2bf(acc[ti][tj][3] + bv);
                *(ushort4*)&Vb[((size_t)(bi * HH + hh) * HD + d) * TT + tok] = pk;
            } else {
#pragma unroll
                for (int reg = 0; reg < 4; reg++) {
                    int m = mbase + reg;
                    float v = acc[ti][tj][reg] + bv;
                    if (EPI == EPI_BIAS_GELU_BF16) {
                        // gelu(v) = v * sigmoid(2u)
                        float u2 = 1.5957691216057308f * (v + 0.044715f * v * v * v);
                        v = v / (1.0f + __expf(-u2));
                        Cb[(size_t)m * N + n] = f2bf(v);
                    } else if (EPI == EPI_QKV) {
                        Cb[(size_t)m * N + n] = f2bf(v);   // Q,K region
                    } else {  // EPI_BIAS_RES_F32
                        v += R[(size_t)m * N + n];
                        Cf[(size_t)m * N + n] = v;
                    }
                }
            }
        }
    }
}

// ---------------- MFMA flash attention: block = (b,h,64-query tile), 4 waves x 16 q ------
// qkvb [B*T][3C] bf16 (Q at h*64, K at C+h*64); vt [B][H][HD][T] bf16; out yb [B*T][C] bf16
__global__ __launch_bounds__(256) void attn_kernel(const unsigned short* __restrict__ qkvb,
                                                   const unsigned short* __restrict__ vt,
                                                   const int* __restrict__ mask,
                                                   unsigned short* __restrict__ yb) {
    __shared__ __align__(16) unsigned short Qs[64][72];
    __shared__ __align__(16) unsigned short Ks[64][72];
    __shared__ __align__(16) unsigned short Vs[64][72];   // Vs[d][key]
    __shared__ __align__(16) unsigned short Ps[4][16][72];
    __shared__ int ms[64];
    int qt = blockIdx.x, h = blockIdx.y, b = blockIdx.z;
    int tid = threadIdx.x;
    int w = tid >> 6, lane = tid & 63, ml = lane & 15, quad = lane >> 4;

    const size_t row3 = 3 * CC;
    const unsigned short* qbase = qkvb + (size_t)(b * TT + qt * 64) * row3 + h * HD;
    const unsigned short* kbase = qkvb + (size_t)(b * TT) * row3 + CC + h * HD;
    const unsigned short* vbase = vt + (size_t)(b * HH + h) * HD * TT;

    // stage Q once: 64 rows x 8 chunks of 8 bf16
#pragma unroll
    for (int i = 0; i < 2; i++) {
        int c = i * 256 + tid; int r = c >> 3, c8 = c & 7;
        *(uint4*)&Qs[r][c8 * 8] = *(const uint4*)(qbase + (size_t)r * row3 + c8 * 8);
    }

    f32x4 o[4] = {};           // o[tj][reg]: row=quad*4+reg, col(d)=tj*16+ml
    float m_i[4], l_i[4];
#pragma unroll
    for (int r = 0; r < 4; r++) { m_i[r] = -1e30f; l_i[r] = 0.f; }

    for (int k0 = 0; k0 < TT; k0 += 64) {
#pragma unroll
        for (int i = 0; i < 2; i++) {
            int c = i * 256 + tid; int r = c >> 3, c8 = c & 7;
            *(uint4*)&Ks[r][c8 * 8] = *(const uint4*)(kbase + (size_t)(k0 + r) * row3 + c8 * 8);
            *(uint4*)&Vs[r][c8 * 8] = *(const uint4*)(vbase + (size_t)r * TT + k0 + c8 * 8);
        }
        if (tid < 64) ms[tid] = mask[b * TT + k0 + tid];
        __syncthreads();

        // S = Q K^T  (16q x 64keys per wave)
        bf16x8 aq0 = *(const bf16x8*)&Qs[w * 16 + ml][quad * 8];
        bf16x8 aq1 = *(const bf16x8*)&Qs[w * 16 + ml][32 + quad * 8];
        float p[4][4];
        float mt[4] = {-1e30f, -1e30f, -1e30f, -1e30f};
#pragma unroll
        for (int tj = 0; tj < 4; tj++) {
            bf16x8 b0 = *(const bf16x8*)&Ks[tj * 16 + ml][quad * 8];
            bf16x8 b1 = *(const bf16x8*)&Ks[tj * 16 + ml][32 + quad * 8];
            f32x4 z = {};
            z = __builtin_amdgcn_mfma_f32_16x16x32_bf16(aq0, b0, z, 0, 0, 0);
            z = __builtin_amdgcn_mfma_f32_16x16x32_bf16(aq1, b1, z, 0, 0, 0);
            bool dead = (ms[tj * 16 + ml] == 0);
#pragma unroll
            for (int r = 0; r < 4; r++) {
                float v = dead ? -1e30f : z[r] * 0.125f;
                p[tj][r] = v;
                mt[r] = fmaxf(mt[r], v);
            }
        }
#pragma unroll
        for (int off = 1; off < 16; off <<= 1)
#pragma unroll
            for (int r = 0; r < 4; r++) mt[r] = fmaxf(mt[r], __shfl_xor(mt[r], off));
        float alpha[4], rs[4];
#pragma unroll
        for (int r = 0; r < 4; r++) {
            float mn = fmaxf(m_i[r], mt[r]);
            alpha[r] = __expf(m_i[r] - mn);
            m_i[r] = mn;
            rs[r] = 0.f;
#pragma unroll
            for (int tj = 0; tj < 4; tj++) {
                float e = __expf(p[tj][r] - mn);
                p[tj][r] = e;
                rs[r] += e;
            }
        }
#pragma unroll
        for (int off = 1; off < 16; off <<= 1)
#pragma unroll
            for (int r = 0; r < 4; r++) rs[r] += __shfl_xor(rs[r], off);
#pragma unroll
        for (int r = 0; r < 4; r++) {
            l_i[r] = l_i[r] * alpha[r] + rs[r];
#pragma unroll
            for (int tj = 0; tj < 4; tj++) o[tj][r] *= alpha[r];
        }
        // P (C-layout) -> LDS bf16 -> A-layout frags  (wave-private strip, no barrier)
#pragma unroll
        for (int tj = 0; tj < 4; tj++)
#pragma unroll
            for (int r = 0; r < 4; r++)
                Ps[w][quad * 4 + r][tj * 16 + ml] = f2bf(p[tj][r]);
        bf16x8 pa0 = *(const bf16x8*)&Ps[w][ml][quad * 8];
        bf16x8 pa1 = *(const bf16x8*)&Ps[w][ml][32 + quad * 8];
#pragma unroll
        for (int tj = 0; tj < 4; tj++) {
            bf16x8 v0 = *(const bf16x8*)&Vs[tj * 16 + ml][quad * 8];
            bf16x8 v1 = *(const bf16x8*)&Vs[tj * 16 + ml][32 + quad * 8];
            o[tj] = __builtin_amdgcn_mfma_f32_16x16x32_bf16(pa0, v0, o[tj], 0, 0, 0);
            o[tj] = __builtin_amdgcn_mfma_f32_16x16x32_bf16(pa1, v1, o[tj], 0, 0, 0);
        }
        __syncthreads();
    }

    // epilogue: q = qt*64 + w*16 + quad*4+r, d = tj*16+ml
#pragma unroll
    for (int r = 0; r < 4; r++) {
        float inv = 1.f / l_i[r];
        int q = qt * 64 + w * 16 + quad * 4 + r;
        unsigned short* yr = yb + (size_t)(b * TT + q) * CC + h * HD;
#pragma unroll
        for (int tj = 0; tj < 4; tj++)
            yr[tj * 16 + ml] = f2bf(o[tj][r] * inv);
    }
}

extern "C" void kernel_launch(void* const* d_in, const int* in_sizes, int n_in,
                              void* d_out, int out_size, void* d_ws, size_t ws_size,
                              hipStream_t stream) {
    const float* x      = (const float*)d_in[0];
    const int*   mask   = (const int*)d_in[1];
    const float* ln1_g  = (const float*)d_in[2];
    const float* ln1_b  = (const float*)d_in[3];
    const float* w_attn = (const float*)d_in[4];
    const float* b_attn = (const float*)d_in[5];
    const float* w_o    = (const float*)d_in[6];
    const float* b_o    = (const float*)d_in[7];
    const float* ln2_g  = (const float*)d_in[8];
    const float* ln2_b  = (const float*)d_in[9];
    const float* w_fc   = (const float*)d_in[10];
    const float* b_fc   = (const float*)d_in[11];
    const float* w_fc2  = (const float*)d_in[12];
    const float* b_fc2  = (const float*)d_in[13];
    float* out = (float*)d_out;

    char* ws = (char*)d_ws;
    size_t off = 0;
    unsigned short* wt_attn = (unsigned short*)(ws + off); off += (size_t)3 * CC * CC * 2;  // 6MB
    unsigned short* wt_o    = (unsigned short*)(ws + off); off += (size_t)CC * CC * 2;      // 2MB
    unsigned short* wt_fc   = (unsigned short*)(ws + off); off += (size_t)4 * CC * CC * 2;  // 8MB
    unsigned short* wt_fc2  = (unsigned short*)(ws + off); off += (size_t)4 * CC * CC * 2;  // 8MB
    // region1 (64MB): qkvb(48) + vt(16), reused as act(64) after attention
    unsigned short* qkvb    = (unsigned short*)(ws + off);
    unsigned short* act     = (unsigned short*)(ws + off); off += (size_t)NT * 3 * CC * 2;
    unsigned short* vt      = (unsigned short*)(ws + off); off += (size_t)BB * CC * TT * 2; // B*H*HD*T
    unsigned short* hb      = (unsigned short*)(ws + off);                                   // 16MB, reused as yb
    unsigned short* yb      = (unsigned short*)(ws + off); off += (size_t)NT * CC * 2;
    float* x1               = (float*)(ws + off); off += (size_t)NT * CC * 4;                // 32MB
    unsigned short* h2b     = (unsigned short*)(ws + off); off += (size_t)NT * CC * 2;       // 16MB

    // weight transpose+convert: W[K,N] f32 -> Wt[N,K] bf16
    tcvt_kernel<<<dim3(3 * CC / 32, CC / 32), 256, 0, stream>>>(w_attn, wt_attn, CC, 3 * CC);
    tcvt_kernel<<<dim3(CC / 32, CC / 32), 256, 0, stream>>>(w_o, wt_o, CC, CC);
    tcvt_kernel<<<dim3(4 * CC / 32, CC / 32), 256, 0, stream>>>(w_fc, wt_fc, CC, 4 * CC);
    tcvt_kernel<<<dim3(CC / 32, 4 * CC / 32), 256, 0, stream>>>(w_fc2, wt_fc2, 4 * CC, CC);

    // 1. LN1 -> bf16
    ln_kernel<<<NT, 256, 0, stream>>>(x, ln1_g, ln1_b, hb);
    // 2. qkv GEMM -> Q,K bf16 [B*T,3C] + V transposed vt[b][h][d][t]
    mgemm<EPI_QKV><<<dim3(3 * CC / 128, NT / 128), 256, 0, stream>>>(
        hb, wt_attn, b_attn, nullptr, nullptr, qkvb, vt, NT, 3 * CC, CC);
    // 3. MFMA flash attention -> yb bf16
    attn_kernel<<<dim3(TT / 64, HH, BB), 256, 0, stream>>>(qkvb, vt, mask, yb);
    // 4. x1 = y @ w_o + b_o + x
    mgemm<EPI_BIAS_RES_F32><<<dim3(CC / 128, NT / 128), 256, 0, stream>>>(
        yb, wt_o, b_o, x, x1, nullptr, nullptr, NT, CC, CC);
    // 5. LN2 -> bf16
    ln_kernel<<<NT, 256, 0, stream>>>(x1, ln2_g, ln2_b, h2b);
    // 6. act = gelu(h2 @ w_fc + b_fc) -> bf16 (into region1; qkvb/vt dead)
    mgemm<EPI_BIAS_GELU_BF16><<<dim3(4 * CC / 128, NT / 128), 256, 0, stream>>>(
        h2b, wt_fc, b_fc, nullptr, nullptr, act, nullptr, NT, 4 * CC, CC);
    // 7. out = act @ w_fc2 + b_fc2 + x1
    mgemm<EPI_BIAS_RES_F32><<<dim3(CC / 128, NT / 128), 256, 0, stream>>>(
        act, wt_fc2, b_fc2, x1, out, nullptr, nullptr, NT, CC, 4 * CC);
}

// Round 6
// 515.126 us; speedup vs baseline: 14.6811x; 1.0104x over previous
//
#include <hip/hip_runtime.h>
#include <math.h>
#include <stdint.h>

#define BB 16
#define TT 512
#define CC 1024
#define HH 16
#define HD 64
#define NT (BB*TT)   // 8192 rows

typedef __bf16 bf16x8 __attribute__((ext_vector_type(8)));
typedef float f32x4 __attribute__((ext_vector_type(4)));

__device__ __forceinline__ unsigned short f2bf(float x) {
    union { float f; unsigned u; } v; v.f = x;
    unsigned r = v.u + 0x7fffu + ((v.u >> 16) & 1u);
    return (unsigned short)(r >> 16);
}

__device__ __forceinline__ void gload_lds16(const void* g, void* l) {
    __builtin_amdgcn_global_load_lds((const __attribute__((address_space(1))) uint32_t*)g,
                                     (__attribute__((address_space(3))) uint32_t*)l, 16, 0, 0);
}

// ---------------- weight transpose+convert: in[K,N] fp32 -> out[N,K] bf16 ----------------
__global__ __launch_bounds__(256) void tcvt_kernel(const float* __restrict__ in,
                                                   unsigned short* __restrict__ out,
                                                   int K, int N) {
    __shared__ float Tt[32][33];
    int n0 = blockIdx.x * 32, k0 = blockIdx.y * 32;
    int t = threadIdx.x;
#pragma unroll
    for (int i = 0; i < 4; i++) {
        int idx = i * 256 + t; int r = idx >> 5, c = idx & 31;
        Tt[r][c] = in[(size_t)(k0 + r) * N + n0 + c];
    }
    __syncthreads();
#pragma unroll
    for (int i = 0; i < 4; i++) {
        int idx = i * 256 + t; int r = idx >> 5, c = idx & 31; // r=n-local, c=k-local
        out[(size_t)(n0 + r) * K + k0 + c] = f2bf(Tt[c][r]);
    }
}

// ---------------- LayerNorm -> bf16 out ----------------
__global__ __launch_bounds__(256) void ln_kernel(const float* __restrict__ x,
                                                 const float* __restrict__ g,
                                                 const float* __restrict__ b,
                                                 unsigned short* __restrict__ out) {
    int row = blockIdx.x;
    const float* xr = x + (size_t)row * CC;
    unsigned short* orow = out + (size_t)row * CC;
    int tid = threadIdx.x;
    float v[4];
    float lsum = 0.f, lsq = 0.f;
#pragma unroll
    for (int i = 0; i < 4; i++) {
        v[i] = xr[tid + 256 * i];
        lsum += v[i];
        lsq  += v[i] * v[i];
    }
    __shared__ float ssum[4], ssq[4];
#pragma unroll
    for (int o = 32; o > 0; o >>= 1) {
        lsum += __shfl_down(lsum, o);
        lsq  += __shfl_down(lsq, o);
    }
    int wid = tid >> 6, lane = tid & 63;
    if (lane == 0) { ssum[wid] = lsum; ssq[wid] = lsq; }
    __syncthreads();
    if (tid == 0) {
        float s = 0.f, q = 0.f;
#pragma unroll
        for (int i = 0; i < 4; i++) { s += ssum[i]; q += ssq[i]; }
        float mu = s / CC;
        float var = q / CC - mu * mu;
        ssum[0] = mu;
        ssq[0] = rsqrtf(var + 1e-5f);
    }
    __syncthreads();
    float mu = ssum[0], rstd = ssq[0];
#pragma unroll
    for (int i = 0; i < 4; i++) {
        int c = tid + 256 * i;
        orow[c] = f2bf((v[i] - mu) * rstd * g[c] + b[c]);
    }
}

// ---------------- bf16 MFMA GEMM: C[M,N] = A[M,K](bf16) @ Bt[N,K](bf16)^T + epilogue ------
// BK=32, double-buffered LDS (2 x 8KB per operand): tile k+1's global_load_lds issued
// BEFORE the MFMA work on tile k, so the barrier's vmcnt drain waits on loads that are
// already ~400cy old. Buffer indices are compile-time constants (2x-unrolled loop) so the
// waitcnt pass can disambiguate ds_reads (cur buf) from in-flight LDS writes (other buf).
// XOR swizzle (as R4): LDS slot (row,c) holds global chunk c ^ ((row>>1)&3), applied at the
// global source; readers use slot quad ^ ((ml>>1)&3) -> all LDS phases 2-way (free).
enum { EPI_BIAS_RES_F32 = 1, EPI_BIAS_GELU_BF16 = 2, EPI_QKV = 3 };

template <int EPI>
__global__ __launch_bounds__(256) void mgemm(const unsigned short* __restrict__ A,
                                             const unsigned short* __restrict__ Bt,
                                             const float* __restrict__ bias,
                                             const float* __restrict__ R,
                                             float* __restrict__ Cf,
                                             unsigned short* __restrict__ Cb,
                                             unsigned short* __restrict__ Vb,
                                             int M, int N, int K) {
    __shared__ __align__(16) unsigned short As[2][128 * 32];
    __shared__ __align__(16) unsigned short Bs[2][128 * 32];
    int tid = threadIdx.x;
    int w = tid >> 6, lane = tid & 63;
    int bm = blockIdx.y * 128, bn = blockIdx.x * 128;
    int wr = (w >> 1) * 64, wc = (w & 1) * 64;

    // staging: thread covers 16B slots {tid, tid+256}; slot s -> row s>>2, chunk slot s&3
    // holds global chunk (s&3) ^ ((s>>3)&3)  (coalesced: 4 tids cover one 64B row)
    int kswz = ((tid & 3) ^ ((tid >> 3) & 3)) * 8;
    const unsigned short* gA0 = A + (size_t)(bm + (tid >> 2)) * K + kswz;
    const unsigned short* gA1 = A + (size_t)(bm + 64 + (tid >> 2)) * K + kswz;
    const unsigned short* gB0 = Bt + (size_t)(bn + (tid >> 2)) * K + kswz;
    const unsigned short* gB1 = Bt + (size_t)(bn + 64 + (tid >> 2)) * K + kswz;

    int ml = lane & 15, quad = lane >> 4;
    int rswz = quad ^ ((ml >> 1) & 3);

    f32x4 acc[4][4] = {};

#define STAGE(buf, k0)                                                  \
    do {                                                                \
        gload_lds16(gA0 + (k0), (char*)As[buf] + w * 1024);             \
        gload_lds16(gA1 + (k0), (char*)As[buf] + 4096 + w * 1024);      \
        gload_lds16(gB0 + (k0), (char*)Bs[buf] + w * 1024);             \
        gload_lds16(gB1 + (k0), (char*)Bs[buf] + 4096 + w * 1024);      \
    } while (0)

#define COMPUTE(buf)                                                    \
    do {                                                                \
        const bf16x8* pa = (const bf16x8*)As[buf] + (wr + ml) * 4 + rswz; \
        const bf16x8* pb = (const bf16x8*)Bs[buf] + (wc + ml) * 4 + rswz; \
        bf16x8 a[4], bb[4];                                             \
        _Pragma("unroll")                                               \
        for (int ti = 0; ti < 4; ti++) a[ti] = pa[ti * 64];             \
        _Pragma("unroll")                                               \
        for (int tj = 0; tj < 4; tj++) bb[tj] = pb[tj * 64];            \
        _Pragma("unroll")                                               \
        for (int ti = 0; ti < 4; ti++)                                  \
            _Pragma("unroll")                                           \
            for (int tj = 0; tj < 4; tj++)                              \
                acc[ti][tj] = __builtin_amdgcn_mfma_f32_16x16x32_bf16(  \
                    a[ti], bb[tj], acc[ti][tj], 0, 0, 0);               \
    } while (0)

    STAGE(0, 0);
    __syncthreads();
    for (int k0 = 0; k0 < K; k0 += 64) {        // K % 64 == 0 always here
        if (k0 + 32 < K) STAGE(1, k0 + 32);
        COMPUTE(0);
        __syncthreads();
        if (k0 + 64 < K) STAGE(0, k0 + 64);
        COMPUTE(1);
        __syncthreads();
    }
#undef STAGE
#undef COMPUTE

    // epilogue: D[m][n]: n = lane&15 (col), m = quad*4 + reg
#pragma unroll
    for (int ti = 0; ti < 4; ti++) {
#pragma unroll
        for (int tj = 0; tj < 4; tj++) {
            int n = bn + wc + tj * 16 + ml;
            int mbase = bm + wr + ti * 16 + quad * 4;
            float bv = bias[n];
            if (EPI == EPI_QKV && n >= 2 * CC) {
                // V: write transposed per-head: vt[b][h][d][t], t=mbase..+3 contiguous
                int d = n & (HD - 1), hh = (n - 2 * CC) >> 6;
                int tok = mbase & (TT - 1), bi = mbase >> 9;
                ushort4 pk;
                pk.x = f2bf(acc[ti][tj][0] + bv);
                pk.y = f2bf(acc[ti][tj][1] + bv);
                pk.z = f2bf(acc[ti][tj][2] + bv);
                pk.w = f2bf(acc[ti][tj][3] + bv);
                *(ushort4*)&Vb[((size_t)(bi * HH + hh) * HD + d) * TT + tok] = pk;
            } else {
#pragma unroll
                for (int reg = 0; reg < 4; reg++) {
                    int m = mbase + reg;
                    float v = acc[ti][tj][reg] + bv;
                    if (EPI == EPI_BIAS_GELU_BF16) {
                        // gelu(v) = v * sigmoid(2u)
                        float u2 = 1.5957691216057308f * (v + 0.044715f * v * v * v);
                        v = v / (1.0f + __expf(-u2));
                        Cb[(size_t)m * N + n] = f2bf(v);
                    } else if (EPI == EPI_QKV) {
                        Cb[(size_t)m * N + n] = f2bf(v);   // Q,K region
                    } else {  // EPI_BIAS_RES_F32
                        v += R[(size_t)m * N + n];
                        Cf[(size_t)m * N + n] = v;
                    }
                }
            }
        }
    }
}

// ---------------- MFMA flash attention: block = (b,h,64-query tile), 4 waves x 16 q ------
// qkvb [B*T][3C] bf16 (Q at h*64, K at C+h*64); vt [B][H][HD][T] bf16; out yb [B*T][C] bf16
__global__ __launch_bounds__(256) void attn_kernel(const unsigned short* __restrict__ qkvb,
                                                   const unsigned short* __restrict__ vt,
                                                   const int* __restrict__ mask,
                                                   unsigned short* __restrict__ yb) {
    __shared__ __align__(16) unsigned short Qs[64][72];
    __shared__ __align__(16) unsigned short Ks[64][72];
    __shared__ __align__(16) unsigned short Vs[64][72];   // Vs[d][key]
    __shared__ __align__(16) unsigned short Ps[4][16][72];
    __shared__ int ms[64];
    int qt = blockIdx.x, h = blockIdx.y, b = blockIdx.z;
    int tid = threadIdx.x;
    int w = tid >> 6, lane = tid & 63, ml = lane & 15, quad = lane >> 4;

    const size_t row3 = 3 * CC;
    const unsigned short* qbase = qkvb + (size_t)(b * TT + qt * 64) * row3 + h * HD;
    const unsigned short* kbase = qkvb + (size_t)(b * TT) * row3 + CC + h * HD;
    const unsigned short* vbase = vt + (size_t)(b * HH + h) * HD * TT;

    // stage Q once: 64 rows x 8 chunks of 8 bf16
#pragma unroll
    for (int i = 0; i < 2; i++) {
        int c = i * 256 + tid; int r = c >> 3, c8 = c & 7;
        *(uint4*)&Qs[r][c8 * 8] = *(const uint4*)(qbase + (size_t)r * row3 + c8 * 8);
    }

    f32x4 o[4] = {};           // o[tj][reg]: row=quad*4+reg, col(d)=tj*16+ml
    float m_i[4], l_i[4];
#pragma unroll
    for (int r = 0; r < 4; r++) { m_i[r] = -1e30f; l_i[r] = 0.f; }

    for (int k0 = 0; k0 < TT; k0 += 64) {
#pragma unroll
        for (int i = 0; i < 2; i++) {
            int c = i * 256 + tid; int r = c >> 3, c8 = c & 7;
            *(uint4*)&Ks[r][c8 * 8] = *(const uint4*)(kbase + (size_t)(k0 + r) * row3 + c8 * 8);
            *(uint4*)&Vs[r][c8 * 8] = *(const uint4*)(vbase + (size_t)r * TT + k0 + c8 * 8);
        }
        if (tid < 64) ms[tid] = mask[b * TT + k0 + tid];
        __syncthreads();

        // S = Q K^T  (16q x 64keys per wave)
        bf16x8 aq0 = *(const bf16x8*)&Qs[w * 16 + ml][quad * 8];
        bf16x8 aq1 = *(const bf16x8*)&Qs[w * 16 + ml][32 + quad * 8];
        float p[4][4];
        float mt[4] = {-1e30f, -1e30f, -1e30f, -1e30f};
#pragma unroll
        for (int tj = 0; tj < 4; tj++) {
            bf16x8 b0 = *(const bf16x8*)&Ks[tj * 16 + ml][quad * 8];
            bf16x8 b1 = *(const bf16x8*)&Ks[tj * 16 + ml][32 + quad * 8];
            f32x4 z = {};
            z = __builtin_amdgcn_mfma_f32_16x16x32_bf16(aq0, b0, z, 0, 0, 0);
            z = __builtin_amdgcn_mfma_f32_16x16x32_bf16(aq1, b1, z, 0, 0, 0);
            bool dead = (ms[tj * 16 + ml] == 0);
#pragma unroll
            for (int r = 0; r < 4; r++) {
                float v = dead ? -1e30f : z[r] * 0.125f;
                p[tj][r] = v;
                mt[r] = fmaxf(mt[r], v);
            }
        }
#pragma unroll
        for (int off = 1; off < 16; off <<= 1)
#pragma unroll
            for (int r = 0; r < 4; r++) mt[r] = fmaxf(mt[r], __shfl_xor(mt[r], off));
        float alpha[4], rs[4];
#pragma unroll
        for (int r = 0; r < 4; r++) {
            float mn = fmaxf(m_i[r], mt[r]);
            alpha[r] = __expf(m_i[r] - mn);
            m_i[r] = mn;
            rs[r] = 0.f;
#pragma unroll
            for (int tj = 0; tj < 4; tj++) {
                float e = __expf(p[tj][r] - mn);
                p[tj][r] = e;
                rs[r] += e;
            }
        }
#pragma unroll
        for (int off = 1; off < 16; off <<= 1)
#pragma unroll
            for (int r = 0; r < 4; r++) rs[r] += __shfl_xor(rs[r], off);
#pragma unroll
        for (int r = 0; r < 4; r++) {
            l_i[r] = l_i[r] * alpha[r] + rs[r];
#pragma unroll
            for (int tj = 0; tj < 4; tj++) o[tj][r] *= alpha[r];
        }
        // P (C-layout) -> LDS bf16 -> A-layout frags  (wave-private strip, no barrier)
#pragma unroll
        for (int tj = 0; tj < 4; tj++)
#pragma unroll
            for (int r = 0; r < 4; r++)
                Ps[w][quad * 4 + r][tj * 16 + ml] = f2bf(p[tj][r]);
        bf16x8 pa0 = *(const bf16x8*)&Ps[w][ml][quad * 8];
        bf16x8 pa1 = *(const bf16x8*)&Ps[w][ml][32 + quad * 8];
#pragma unroll
        for (int tj = 0; tj < 4; tj++) {
            bf16x8 v0 = *(const bf16x8*)&Vs[tj * 16 + ml][quad * 8];
            bf16x8 v1 = *(const bf16x8*)&Vs[tj * 16 + ml][32 + quad * 8];
            o[tj] = __builtin_amdgcn_mfma_f32_16x16x32_bf16(pa0, v0, o[tj], 0, 0, 0);
            o[tj] = __builtin_amdgcn_mfma_f32_16x16x32_bf16(pa1, v1, o[tj], 0, 0, 0);
        }
        __syncthreads();
    }

    // epilogue: q = qt*64 + w*16 + quad*4+r, d = tj*16+ml
#pragma unroll
    for (int r = 0; r < 4; r++) {
        float inv = 1.f / l_i[r];
        int q = qt * 64 + w * 16 + quad * 4 + r;
        unsigned short* yr = yb + (size_t)(b * TT + q) * CC + h * HD;
#pragma unroll
        for (int tj = 0; tj < 4; tj++)
            yr[tj * 16 + ml] = f2bf(o[tj][r] * inv);
    }
}

extern "C" void kernel_launch(void* const* d_in, const int* in_sizes, int n_in,
                              void* d_out, int out_size, void* d_ws, size_t ws_size,
                              hipStream_t stream) {
    const float* x      = (const float*)d_in[0];
    const int*   mask   = (const int*)d_in[1];
    const float* ln1_g  = (const float*)d_in[2];
    const float* ln1_b  = (const float*)d_in[3];
    const float* w_attn = (const float*)d_in[4];
    const float* b_attn = (const float*)d_in[5];
    const float* w_o    = (const float*)d_in[6];
    const float* b_o    = (const float*)d_in[7];
    const float* ln2_g  = (const float*)d_in[8];
    const float* ln2_b  = (const float*)d_in[9];
    const float* w_fc   = (const float*)d_in[10];
    const float* b_fc   = (const float*)d_in[11];
    const float* w_fc2  = (const float*)d_in[12];
    const float* b_fc2  = (const float*)d_in[13];
    float* out = (float*)d_out;

    char* ws = (char*)d_ws;
    size_t off = 0;
    unsigned short* wt_attn = (unsigned short*)(ws + off); off += (size_t)3 * CC * CC * 2;  // 6MB
    unsigned short* wt_o    = (unsigned short*)(ws + off); off += (size_t)CC * CC * 2;      // 2MB
    unsigned short* wt_fc   = (unsigned short*)(ws + off); off += (size_t)4 * CC * CC * 2;  // 8MB
    unsigned short* wt_fc2  = (unsigned short*)(ws + off); off += (size_t)4 * CC * CC * 2;  // 8MB
    // region1 (64MB): qkvb(48) + vt(16), reused as act(64) after attention
    unsigned short* qkvb    = (unsigned short*)(ws + off);
    unsigned short* act     = (unsigned short*)(ws + off); off += (size_t)NT * 3 * CC * 2;
    unsigned short* vt      = (unsigned short*)(ws + off); off += (size_t)BB * CC * TT * 2; // B*H*HD*T
    unsigned short* hb      = (unsigned short*)(ws + off);                                   // 16MB, reused as yb
    unsigned short* yb      = (unsigned short*)(ws + off); off += (size_t)NT * CC * 2;
    float* x1               = (float*)(ws + off); off += (size_t)NT * CC * 4;                // 32MB
    unsigned short* h2b     = (unsigned short*)(ws + off); off += (size_t)NT * CC * 2;       // 16MB

    // weight transpose+convert: W[K,N] f32 -> Wt[N,K] bf16
    tcvt_kernel<<<dim3(3 * CC / 32, CC / 32), 256, 0, stream>>>(w_attn, wt_attn, CC, 3 * CC);
    tcvt_kernel<<<dim3(CC / 32, CC / 32), 256, 0, stream>>>(w_o, wt_o, CC, CC);
    tcvt_kernel<<<dim3(4 * CC / 32, CC / 32), 256, 0, stream>>>(w_fc, wt_fc, CC, 4 * CC);
    tcvt_kernel<<<dim3(CC / 32, 4 * CC / 32), 256, 0, stream>>>(w_fc2, wt_fc2, 4 * CC, CC);

    // 1. LN1 -> bf16
    ln_kernel<<<NT, 256, 0, stream>>>(x, ln1_g, ln1_b, hb);
    // 2. qkv GEMM -> Q,K bf16 [B*T,3C] + V transposed vt[b][h][d][t]
    mgemm<EPI_QKV><<<dim3(3 * CC / 128, NT / 128), 256, 0, stream>>>(
        hb, wt_attn, b_attn, nullptr, nullptr, qkvb, vt, NT, 3 * CC, CC);
    // 3. MFMA flash attention -> yb bf16
    attn_kernel<<<dim3(TT / 64, HH, BB), 256, 0, stream>>>(qkvb, vt, mask, yb);
    // 4. x1 = y @ w_o + b_o + x
    mgemm<EPI_BIAS_RES_F32><<<dim3(CC / 128, NT / 128), 256, 0, stream>>>(
        yb, wt_o, b_o, x, x1, nullptr, nullptr, NT, CC, CC);
    // 5. LN2 -> bf16
    ln_kernel<<<NT, 256, 0, stream>>>(x1, ln2_g, ln2_b, h2b);
    // 6. act = gelu(h2 @ w_fc + b_fc) -> bf16 (into region1; qkvb/vt dead)
    mgemm<EPI_BIAS_GELU_BF16><<<dim3(4 * CC / 128, NT / 128), 256, 0, stream>>>(
        h2b, wt_fc, b_fc, nullptr, nullptr, act, nullptr, NT, 4 * CC, CC);
    // 7. out = act @ w_fc2 + b_fc2 + x1
    mgemm<EPI_BIAS_RES_F32><<<dim3(CC / 128, NT / 128), 256, 0, stream>>>(
        act, wt_fc2, b_fc2, x1, out, nullptr, nullptr, NT, CC, 4 * CC);
}